// Round 9
// baseline (783.411 us; speedup 1.0000x reference)
//
#include <hip/hip_runtime.h>
#include <hip/hip_bf16.h>
#include <math.h>

#define NN 50000
#define IN_F 128
#define DD 64
#define HH 4
#define CC 10
#define GG 64
#define NEG_SLOPE 0.2f

typedef __attribute__((ext_vector_type(8))) short bf16x8;
typedef __attribute__((ext_vector_type(4))) float f32x4;

__device__ inline ushort f2bf(float f) {
    unsigned u = __float_as_uint(f);
    unsigned r = (u + 0x7fffu + ((u >> 16) & 1u)) >> 16;
    return (ushort)r;
}
__device__ inline float bf2f(ushort b) { return __uint_as_float(((unsigned)b) << 16); }

// fp8 e4m3fn software encode (RNE) / decode — exact for normals + denormals
__device__ inline unsigned f2fp8(float f) {
    float a = fabsf(f);
    a = fminf(a, 448.f);
    unsigned s = (__float_as_uint(f) >> 31) << 7;
    unsigned bits;
    if (a < 0.015625f) {  // < 2^-6: denormal, value = m * 2^-9
        bits = (unsigned)__float2int_rn(a * 512.f);  // 0..8 (8 carries into e=1,m=0)
    } else {
        unsigned u = __float_as_uint(a);
        u += 0x7ffffu + ((u >> 20) & 1u);  // RNE at dropped bit 20
        bits = (u >> 20) - (120u << 3);
        bits = min(bits, 0x7Eu);
    }
    return s | bits;
}
__device__ inline float fp82f(unsigned b) {
    unsigned u = ((b & 0x80u) << 24) | ((b & 0x7fu) << 20);
    return __uint_as_float(u) * 0x1p120f;
}

// ---------------- wave helpers ----------------
__device__ inline float wave_max(float v) {
#pragma unroll
    for (int o = 32; o > 0; o >>= 1) v = fmaxf(v, __shfl_xor(v, o));
    return v;
}
__device__ inline float wave_sum(float v) {
#pragma unroll
    for (int o = 32; o > 0; o >>= 1) v += __shfl_xor(v, o);
    return v;
}

// ---------------- CSR build ----------------
__global__ void hist_kernel(const int* __restrict__ dst, int E, int* __restrict__ counts) {
    int i = blockIdx.x * blockDim.x + threadIdx.x;
    if (i < E) atomicAdd(&counts[dst[i]], 1);
}

__global__ __launch_bounds__(256) void scan_blk(const int* __restrict__ counts,
                                                int* __restrict__ excl,
                                                int* __restrict__ bsum, int n) {
    __shared__ int sh[256];
    int t = threadIdx.x;
    int i = blockIdx.x * 256 + t;
    int v = (i < n) ? counts[i] : 0;
    sh[t] = v;
    __syncthreads();
#pragma unroll
    for (int o = 1; o < 256; o <<= 1) {
        int u = (t >= o) ? sh[t - o] : 0;
        __syncthreads();
        sh[t] += u;
        __syncthreads();
    }
    if (i < n) excl[i] = sh[t] - v;
    if (t == 255) bsum[blockIdx.x] = sh[255];
}

__global__ __launch_bounds__(256) void scan_top(int* __restrict__ bsum, int nb) {
    __shared__ int sh[256];
    int t = threadIdx.x;
    int v = (t < nb) ? bsum[t] : 0;
    sh[t] = v;
    __syncthreads();
#pragma unroll
    for (int o = 1; o < 256; o <<= 1) {
        int u = (t >= o) ? sh[t - o] : 0;
        __syncthreads();
        sh[t] += u;
        __syncthreads();
    }
    if (t < nb) bsum[t] = sh[t] - v;  // exclusive
}

__global__ __launch_bounds__(256) void scan_fin(const int* __restrict__ excl,
                                                const int* __restrict__ bsum,
                                                int* __restrict__ row_ptr,
                                                int* __restrict__ fill, int n, int E) {
    int i = blockIdx.x * blockDim.x + threadIdx.x;
    if (i < n) {
        int r = excl[i] + bsum[i >> 8];
        row_ptr[i] = r;
        fill[i] = r;
    }
    if (i == 0) row_ptr[n] = E;
}

__global__ void scatter_kernel(const int* __restrict__ src, const int* __restrict__ dst,
                               int E, int* __restrict__ fill, int* __restrict__ col_src) {
    int i = blockIdx.x * blockDim.x + threadIdx.x;
    if (i < E) {
        int p = atomicAdd(&fill[dst[i]], 1);
        col_src[p] = src[i];
    }
}

// ---------------- W -> transposed, k-blocked, bf16: Wt[kb][n][kk] ----------------
__global__ void wconv_kernel(const float* __restrict__ W, int K, int N,
                             ushort* __restrict__ thi) {
    int i = blockIdx.x * blockDim.x + threadIdx.x;
    if (i >= K * N) return;
    int k = i / N, n = i - k * N;
    size_t o = ((size_t)(k >> 5) * N + n) * 32 + (k & 31);
    thi[o] = f2bf(W[i]);
}

// ---------------- MFMA GEMM: barrier-free, no LDS; B fragments direct from global ----------------
// A: AF32 ? fp32 [M][K] (split in-register) : pre-split hi/lo bf16 [M][K].
// W: blocked [K/32][N][32] bf16 (fragment = contiguous 16B, wave load = 1KB coalesced, L1-resident).
// z out: H=4 -> fp8 packed [r][d][h]; H=1 -> bf16 [r][d].
template <int N, int H, bool AF32>
__global__ __launch_bounds__(256) void gemm_mfma_eler(
    const void* __restrict__ A0, const ushort* __restrict__ Alo,
    const ushort* __restrict__ Wthi,
    void* __restrict__ ztv, const float* __restrict__ al, const float* __restrict__ ar,
    float* __restrict__ el, float* __restrict__ er, int M, int K) {
    constexpr int NT = N / 16;
    const int t = threadIdx.x;
    const int w = t >> 6, lane = t & 63;
    const int cl = lane & 15, g = lane >> 4;
    const int bm = blockIdx.x * 64;
    const int arow = bm + 16 * w + cl;
    const bool aval = arow < M;
    const size_t abase = (size_t)arow * K;
    const float* Af = (const float*)A0;
    const ushort* Ahi = (const ushort*)A0;

    f32x4 acc[NT];
#pragma unroll
    for (int nt = 0; nt < NT; ++nt) acc[nt] = (f32x4){0.f, 0.f, 0.f, 0.f};

    const int nkb = K >> 5;
    for (int kb = 0; kb < nkb; ++kb) {
        bf16x8 a_hi = {0, 0, 0, 0, 0, 0, 0, 0};
        bf16x8 a_lo = {0, 0, 0, 0, 0, 0, 0, 0};
        if (aval) {
            if (AF32) {
                float4 f0 = *(const float4*)(Af + abase + kb * 32 + g * 8);
                float4 f1 = *(const float4*)(Af + abase + kb * 32 + g * 8 + 4);
                float fv[8] = {f0.x, f0.y, f0.z, f0.w, f1.x, f1.y, f1.z, f1.w};
#pragma unroll
                for (int q = 0; q < 8; ++q) {
                    ushort hb = f2bf(fv[q]);
                    a_hi[q] = (short)hb;
                    a_lo[q] = (short)f2bf(fv[q] - bf2f(hb));
                }
            } else {
                a_hi = *(const bf16x8*)(Ahi + abase + kb * 32 + g * 8);
                a_lo = *(const bf16x8*)(Alo + abase + kb * 32 + g * 8);
            }
        }
        const ushort* wb = Wthi + (size_t)kb * N * 32;
#pragma unroll
        for (int nt = 0; nt < NT; ++nt) {
            bf16x8 b_hi = *(const bf16x8*)(wb + (16 * nt + cl) * 32 + g * 8);
            acc[nt] = __builtin_amdgcn_mfma_f32_16x16x32_bf16(a_hi, b_hi, acc[nt], 0, 0, 0);
            acc[nt] = __builtin_amdgcn_mfma_f32_16x16x32_bf16(a_lo, b_hi, acc[nt], 0, 0, 0);
        }
    }

    // z store. Lane holds C[r0+j][16nt+cl], r0 = bm+16w+4g.
    const int r0 = bm + 16 * w + 4 * g;
    if (H == 4) {
        unsigned char* zf8 = (unsigned char*)ztv;
#pragma unroll
        for (int tt = 0; tt < 4; ++tt) {
#pragma unroll
            for (int j = 0; j < 4; ++j) {
                int r = r0 + j;
                if (r < M) {
                    unsigned pw = f2fp8(acc[tt][j]) | (f2fp8(acc[4 + tt][j]) << 8) |
                                  (f2fp8(acc[8 + tt][j]) << 16) | (f2fp8(acc[12 + tt][j]) << 24);
                    *(unsigned*)&zf8[(size_t)r * 256 + (16 * tt + cl) * 4] = pw;
                }
            }
        }
    } else {
        ushort* zt = (ushort*)ztv;
#pragma unroll
        for (int nt = 0; nt < NT; ++nt) {
#pragma unroll
            for (int j = 0; j < 4; ++j) {
                int r = r0 + j;
                if (r < M) zt[(size_t)r * N + 16 * nt + cl] = f2bf(acc[nt][j]);
            }
        }
    }
    // fused el/er
#pragma unroll
    for (int h = 0; h < H; ++h) {
        float pl[4] = {0.f, 0.f, 0.f, 0.f};
        float pr[4] = {0.f, 0.f, 0.f, 0.f};
#pragma unroll
        for (int tt = 0; tt < 4; ++tt) {
            int nt = 4 * h + tt;
            float av = al[h * DD + 16 * tt + cl];
            float rv = ar[h * DD + 16 * tt + cl];
#pragma unroll
            for (int j = 0; j < 4; ++j) {
                pl[j] += acc[nt][j] * av;
                pr[j] += acc[nt][j] * rv;
            }
        }
#pragma unroll
        for (int j = 0; j < 4; ++j) {
#pragma unroll
            for (int o = 1; o < 16; o <<= 1) {
                pl[j] += __shfl_xor(pl[j], o);
                pr[j] += __shfl_xor(pr[j], o);
            }
        }
        if (cl == 0) {
#pragma unroll
            for (int j = 0; j < 4; ++j) {
                int r = r0 + j;
                if (r < M) {
                    el[(size_t)r * H + h] = pl[j];
                    er[(size_t)r * H + h] = pr[j];
                }
            }
        }
    }
}

// ---------------- fused attention + aggregation: one wave per dst ----------------
// phase A (lane=edge): alpha computed once per edge -> per-wave LDS
// phase B (lane=feature): acc[h] += alpha[j][h] * z[src_j]  (z: fp8 for H=4, bf16 for H=1)
template <int H, bool SPLIT>
__global__ __launch_bounds__(256) void agg_fused(const void* __restrict__ ztv,
                                                 const float* __restrict__ el,
                                                 const float* __restrict__ er,
                                                 const int* __restrict__ row_ptr,
                                                 const int* __restrict__ col_src,
                                                 float* __restrict__ outf,
                                                 ushort* __restrict__ ohi,
                                                 ushort* __restrict__ olo) {
    __shared__ float alf[4][64][H];  // per-wave alpha slab
    __shared__ int als[4][64];       // per-wave src ids
    const unsigned char* zf8 = (const unsigned char*)ztv;
    const ushort* zt16 = (const ushort*)ztv;
    const int wid = threadIdx.x >> 6;
    const int lane = threadIdx.x & 63;
    int v = blockIdx.x * 4 + wid;
    if (v >= NN) return;
    int start = row_ptr[v], end = row_ptr[v + 1];
    int deg = end - start;
    float erd[H], acc[H];
#pragma unroll
    for (int h = 0; h < H; ++h) {
        erd[h] = er[(size_t)v * H + h];
        acc[h] = 0.f;
    }

    auto agg_chunk = [&](int cnt) {
        int j = 0;
        for (; j + 4 <= cnt; j += 4) {
            int s0 = als[wid][j + 0], s1 = als[wid][j + 1];
            int s2 = als[wid][j + 2], s3 = als[wid][j + 3];
            if (H == 4) {
                f32x4 a0 = *(const f32x4*)&alf[wid][j + 0][0];
                f32x4 a1 = *(const f32x4*)&alf[wid][j + 1][0];
                f32x4 a2 = *(const f32x4*)&alf[wid][j + 2][0];
                f32x4 a3 = *(const f32x4*)&alf[wid][j + 3][0];
                unsigned z0 = *(const unsigned*)&zf8[(size_t)s0 * 256 + lane * 4];
                unsigned z1 = *(const unsigned*)&zf8[(size_t)s1 * 256 + lane * 4];
                unsigned z2 = *(const unsigned*)&zf8[(size_t)s2 * 256 + lane * 4];
                unsigned z3 = *(const unsigned*)&zf8[(size_t)s3 * 256 + lane * 4];
#pragma unroll
                for (int h = 0; h < 4; ++h) {
                    acc[h] += a0[h] * fp82f((z0 >> (8 * h)) & 0xffu);
                    acc[h] += a1[h] * fp82f((z1 >> (8 * h)) & 0xffu);
                    acc[h] += a2[h] * fp82f((z2 >> (8 * h)) & 0xffu);
                    acc[h] += a3[h] * fp82f((z3 >> (8 * h)) & 0xffu);
                }
            } else {
                float a0 = alf[wid][j + 0][0], a1 = alf[wid][j + 1][0];
                float a2 = alf[wid][j + 2][0], a3 = alf[wid][j + 3][0];
                ushort z0 = zt16[(size_t)s0 * 64 + lane];
                ushort z1 = zt16[(size_t)s1 * 64 + lane];
                ushort z2 = zt16[(size_t)s2 * 64 + lane];
                ushort z3 = zt16[(size_t)s3 * 64 + lane];
                acc[0] += a0 * bf2f(z0);
                acc[0] += a1 * bf2f(z1);
                acc[0] += a2 * bf2f(z2);
                acc[0] += a3 * bf2f(z3);
            }
        }
        for (; j < cnt; ++j) {
            int s = als[wid][j];
            if (H == 4) {
                f32x4 a = *(const f32x4*)&alf[wid][j][0];
                unsigned z = *(const unsigned*)&zf8[(size_t)s * 256 + lane * 4];
#pragma unroll
                for (int h = 0; h < 4; ++h) acc[h] += a[h] * fp82f((z >> (8 * h)) & 0xffu);
            } else {
                acc[0] += alf[wid][j][0] * bf2f(zt16[(size_t)s * 64 + lane]);
            }
        }
    };

    if (deg <= 64) {
        bool valid = lane < deg;
        int s = col_src[valid ? start + lane : start];
        als[wid][lane] = s;
        float e[H];
        if (H == 4) {
            f32x4 ev = *(const f32x4*)&el[(size_t)s * 4];
#pragma unroll
            for (int h = 0; h < 4; ++h) {
                float x = ev[h] + erd[h];
                x = (x >= 0.f) ? x : NEG_SLOPE * x;
                e[h] = valid ? x : -1e30f;
            }
        } else {
            float x = el[s] + erd[0];
            x = (x >= 0.f) ? x : NEG_SLOPE * x;
            e[0] = valid ? x : -1e30f;
        }
#pragma unroll
        for (int h = 0; h < H; ++h) {
            float m = wave_max(e[h]);
            float ex = valid ? __expf(e[h] - m) : 0.f;
            float den = wave_sum(ex);
            alf[wid][lane][h] = ex * (1.f / den);
        }
        __builtin_amdgcn_wave_barrier();
        agg_chunk(deg);
    } else {
        float m[H];
#pragma unroll
        for (int h = 0; h < H; ++h) m[h] = -1e30f;
        for (int base = start; base < end; base += 64) {
            int i = base + lane;
            bool valid = i < end;
            int s = col_src[valid ? i : start];
#pragma unroll
            for (int h = 0; h < H; ++h) {
                float x = el[(size_t)s * H + h] + erd[h];
                x = (x >= 0.f) ? x : NEG_SLOPE * x;
                m[h] = fmaxf(m[h], valid ? x : -1e30f);
            }
        }
        float den[H];
#pragma unroll
        for (int h = 0; h < H; ++h) {
            m[h] = wave_max(m[h]);
            den[h] = 0.f;
        }
        for (int base = start; base < end; base += 64) {
            int i = base + lane;
            bool valid = i < end;
            int s = col_src[valid ? i : start];
#pragma unroll
            for (int h = 0; h < H; ++h) {
                float x = el[(size_t)s * H + h] + erd[h];
                x = (x >= 0.f) ? x : NEG_SLOPE * x;
                den[h] += valid ? __expf(x - m[h]) : 0.f;
            }
        }
        float inv[H];
#pragma unroll
        for (int h = 0; h < H; ++h) inv[h] = 1.f / wave_sum(den[h]);
        for (int base = start; base < end; base += 64) {
            int i = base + lane;
            bool valid = i < end;
            int s = col_src[valid ? i : start];
            als[wid][lane] = s;
#pragma unroll
            for (int h = 0; h < H; ++h) {
                float x = el[(size_t)s * H + h] + erd[h];
                x = (x >= 0.f) ? x : NEG_SLOPE * x;
                alf[wid][lane][h] = valid ? __expf(x - m[h]) * inv[h] : 0.f;
            }
            __builtin_amdgcn_wave_barrier();
            int cnt = min(64, end - base);
            agg_chunk(cnt);
            __builtin_amdgcn_wave_barrier();
        }
    }

#pragma unroll
    for (int h = 0; h < H; ++h) {
        float r = acc[h];
        r = (r > 0.f) ? r : 0.f;  // fused ReLU
        size_t idx = (size_t)v * H * DD + h * DD + lane;
        if (SPLIT) {
            ushort hb = f2bf(r);
            ohi[idx] = hb;
            olo[idx] = f2bf(r - bf2f(hb));
        } else {
            outf[idx] = r;
        }
    }
}

// ---------------- pooling ----------------
__device__ inline int lower_bound_dev(const int* a, int n, int v) {
    int lo = 0, hi = n;
    while (lo < hi) {
        int mid = (lo + hi) >> 1;
        if (a[mid] < v) lo = mid + 1; else hi = mid;
    }
    return lo;
}

__global__ __launch_bounds__(256) void pool_kernel(const float* __restrict__ x,
                                                   const int* __restrict__ gid,
                                                   float* __restrict__ pooled,
                                                   float* __restrict__ gcnt) {
    int g = blockIdx.x;
    int start = lower_bound_dev(gid, NN, g);
    int end = lower_bound_dev(gid, NN, g + 1);
    int lane = threadIdx.x & 63;
    int w = threadIdx.x >> 6;
    float acc = 0.f;
    for (int i = start + w; i < end; i += 4) acc += x[(size_t)i * DD + lane];
    __shared__ float red[4][DD];
    red[w][lane] = acc;
    __syncthreads();
    if (w == 0) {
        float s = red[0][lane] + red[1][lane] + red[2][lane] + red[3][lane];
        pooled[g * DD + lane] = s;
        if (lane == 0) gcnt[g] = (float)(end - start);
    }
}

// ---------------- head ----------------
__global__ __launch_bounds__(64) void head_kernel(const float* __restrict__ pooled,
                                                  const float* __restrict__ gcnt,
                                                  const float* __restrict__ fc1w,
                                                  const float* __restrict__ fc1b,
                                                  const float* __restrict__ fc2w,
                                                  const float* __restrict__ fc2b,
                                                  float* __restrict__ out) {
    __shared__ float P[GG][DD + 1];
    __shared__ float Y1[GG][DD + 1];
    int g = threadIdx.x;
    float c = fmaxf(gcnt[g], 1.0f);
    for (int k = 0; k < DD; ++k) P[g][k] = pooled[g * DD + k] / c;
    __syncthreads();
    for (int j = 0; j < DD; ++j) {
        float s = fc1b[j];
        for (int k = 0; k < DD; ++k) s += P[g][k] * fc1w[k * DD + j];
        Y1[g][j] = (s > 0.f) ? s : expm1f(s);
    }
    __syncthreads();
    float y2[CC];
    for (int c2 = 0; c2 < CC; ++c2) {
        float s = fc2b[c2];
        for (int j = 0; j < DD; ++j) s += Y1[g][j] * fc2w[j * CC + c2];
        y2[c2] = s;
    }
    for (int c2 = 0; c2 < CC; ++c2) {
        float m = y2[c2];
#pragma unroll
        for (int o = 32; o > 0; o >>= 1) m = fmaxf(m, __shfl_xor(m, o));
        float sexp = __expf(y2[c2] - m);
#pragma unroll
        for (int o = 32; o > 0; o >>= 1) sexp += __shfl_xor(sexp, o);
        out[g * CC + c2] = y2[c2] - m - logf(sexp);
    }
}

// ---------------- launcher ----------------
extern "C" void kernel_launch(void* const* d_in, const int* in_sizes, int n_in,
                              void* d_out, int out_size, void* d_ws, size_t ws_size,
                              hipStream_t stream) {
    const float* h    = (const float*)d_in[0];
    const int* src    = (const int*)d_in[1];
    const int* dst    = (const int*)d_in[2];
    const int* gid    = (const int*)d_in[3];
    const float* W0   = (const float*)d_in[4];
    const float* al0  = (const float*)d_in[5];
    const float* ar0  = (const float*)d_in[6];
    const float* W1   = (const float*)d_in[7];
    const float* al1  = (const float*)d_in[8];
    const float* ar1  = (const float*)d_in[9];
    const float* W2   = (const float*)d_in[10];
    const float* al2  = (const float*)d_in[11];
    const float* ar2  = (const float*)d_in[12];
    const float* W3   = (const float*)d_in[13];
    const float* al3  = (const float*)d_in[14];
    const float* ar3  = (const float*)d_in[15];
    const float* fc1w = (const float*)d_in[16];
    const float* fc1b = (const float*)d_in[17];
    const float* fc2w = (const float*)d_in[18];
    const float* fc2b = (const float*)d_in[19];
    const int E = in_sizes[1];

    char* wsb = (char*)d_ws;
    size_t off = 0;
    auto alloc = [&](size_t bytes) -> void* {
        void* p = wsb + off;
        off = (off + bytes + 255) & ~(size_t)255;
        return p;
    };
    unsigned char* zf8 = (unsigned char*)alloc((size_t)NN * 256);  // z fp8 packed [v][d][h] (layers 0-2)
    ushort* zt16    = (ushort*)alloc((size_t)NN * DD * 2);         // z bf16 [v][d] (layer 3)
    ushort* Ahi     = (ushort*)alloc((size_t)NN * 256 * 2);
    ushort* Alo     = (ushort*)alloc((size_t)NN * 256 * 2);
    float*  bufA    = (float*)alloc((size_t)NN * DD * 4);
    float*  el      = (float*)alloc((size_t)NN * HH * 4);
    float*  er      = (float*)alloc((size_t)NN * HH * 4);
    int*    counts  = (int*)alloc((size_t)NN * 4);
    int*    row_ptr = (int*)alloc((size_t)(NN + 1) * 4);
    int*    fill    = (int*)alloc((size_t)NN * 4);
    int*    excl    = (int*)alloc((size_t)NN * 4);
    int*    bsum    = (int*)alloc((size_t)256 * 4);
    int*    col_src = (int*)alloc((size_t)E * 4);
    float*  pooled  = (float*)alloc((size_t)GG * DD * 4);
    float*  gcnt    = (float*)alloc((size_t)GG * 4);
    ushort* w0h     = (ushort*)alloc((size_t)IN_F * 256 * 2);
    ushort* w1h     = (ushort*)alloc((size_t)256 * 256 * 2);
    ushort* w2h     = (ushort*)alloc((size_t)256 * 256 * 2);
    ushort* w3h     = (ushort*)alloc((size_t)256 * 64 * 2);

    // ---- CSR build ----
    hipMemsetAsync(counts, 0, (size_t)NN * 4, stream);
    int eg = (E + 255) / 256;
    const int nScanBlk = (NN + 255) / 256;  // 196
    hist_kernel<<<eg, 256, 0, stream>>>(dst, E, counts);
    scan_blk<<<nScanBlk, 256, 0, stream>>>(counts, excl, bsum, NN);
    scan_top<<<1, 256, 0, stream>>>(bsum, nScanBlk);
    scan_fin<<<nScanBlk, 256, 0, stream>>>(excl, bsum, row_ptr, fill, NN, E);
    scatter_kernel<<<eg, 256, 0, stream>>>(src, dst, E, fill, col_src);

    // ---- weight conversions (bf16, transposed k-blocked) ----
    wconv_kernel<<<(IN_F * 256 + 255) / 256, 256, 0, stream>>>(W0, IN_F, 256, w0h);
    wconv_kernel<<<(256 * 256 + 255) / 256, 256, 0, stream>>>(W1, 256, 256, w1h);
    wconv_kernel<<<(256 * 256 + 255) / 256, 256, 0, stream>>>(W2, 256, 256, w2h);
    wconv_kernel<<<(256 * 64 + 255) / 256, 256, 0, stream>>>(W3, 256, 64, w3h);

    const int gemmGrid = (NN + 63) / 64;  // 782
    const int waveBlocks = (NN + 3) / 4;  // 12500

    // ---- layer 0 (K=128, N=256, H=4): A = h fp32, split in-register ----
    gemm_mfma_eler<256, 4, true><<<gemmGrid, 256, 0, stream>>>(h, nullptr, w0h, zf8, al0, ar0, el, er, NN, IN_F);
    agg_fused<4, true><<<waveBlocks, 256, 0, stream>>>(zf8, el, er, row_ptr, col_src, nullptr, Ahi, Alo);

    // ---- layer 1 ----
    gemm_mfma_eler<256, 4, false><<<gemmGrid, 256, 0, stream>>>(Ahi, Alo, w1h, zf8, al1, ar1, el, er, NN, 256);
    agg_fused<4, true><<<waveBlocks, 256, 0, stream>>>(zf8, el, er, row_ptr, col_src, nullptr, Ahi, Alo);

    // ---- layer 2 ----
    gemm_mfma_eler<256, 4, false><<<gemmGrid, 256, 0, stream>>>(Ahi, Alo, w2h, zf8, al2, ar2, el, er, NN, 256);
    agg_fused<4, true><<<waveBlocks, 256, 0, stream>>>(zf8, el, er, row_ptr, col_src, nullptr, Ahi, Alo);

    // ---- layer 3 (K=256, N=64, H=1): z bf16 ----
    gemm_mfma_eler<64, 1, false><<<gemmGrid, 256, 0, stream>>>(Ahi, Alo, w3h, zt16, al3, ar3, el, er, NN, 256);
    agg_fused<1, false><<<waveBlocks, 256, 0, stream>>>(zt16, el, er, row_ptr, col_src, bufA, nullptr, nullptr);

    // ---- pooling + head ----
    pool_kernel<<<GG, 256, 0, stream>>>(bufA, gid, pooled, gcnt);
    head_kernel<<<1, 64, 0, stream>>>(pooled, gcnt, fc1w, fc1b, fc2w, fc2b, (float*)d_out);
}

// Round 11
// 614.520 us; speedup vs baseline: 1.2748x; 1.2748x over previous
//
#include <hip/hip_runtime.h>
#include <hip/hip_bf16.h>
#include <math.h>

#define NN 50000
#define IN_F 128
#define DD 64
#define HH 4
#define CC 10
#define GG 64
#define NEG_SLOPE 0.2f

typedef __attribute__((ext_vector_type(8))) short bf16x8;
typedef __attribute__((ext_vector_type(4))) float f32x4;
typedef __attribute__((ext_vector_type(4))) unsigned short u16x4;

__device__ inline ushort f2bf(float f) {
    unsigned u = __float_as_uint(f);
    unsigned r = (u + 0x7fffu + ((u >> 16) & 1u)) >> 16;
    return (ushort)r;
}
__device__ inline float bf2f(ushort b) { return __uint_as_float(((unsigned)b) << 16); }

// ---------------- wave helpers ----------------
__device__ inline float wave_max(float v) {
#pragma unroll
    for (int o = 32; o > 0; o >>= 1) v = fmaxf(v, __shfl_xor(v, o));
    return v;
}
__device__ inline float wave_sum(float v) {
#pragma unroll
    for (int o = 32; o > 0; o >>= 1) v += __shfl_xor(v, o);
    return v;
}

// ---------------- CSR build ----------------
__global__ void hist_kernel(const int* __restrict__ dst, int E, int* __restrict__ counts) {
    int i = blockIdx.x * blockDim.x + threadIdx.x;
    if (i < E) atomicAdd(&counts[dst[i]], 1);
}

__global__ __launch_bounds__(256) void scan_blk(const int* __restrict__ counts,
                                                int* __restrict__ excl,
                                                int* __restrict__ bsum, int n) {
    __shared__ int sh[256];
    int t = threadIdx.x;
    int i = blockIdx.x * 256 + t;
    int v = (i < n) ? counts[i] : 0;
    sh[t] = v;
    __syncthreads();
#pragma unroll
    for (int o = 1; o < 256; o <<= 1) {
        int u = (t >= o) ? sh[t - o] : 0;
        __syncthreads();
        sh[t] += u;
        __syncthreads();
    }
    if (i < n) excl[i] = sh[t] - v;
    if (t == 255) bsum[blockIdx.x] = sh[255];
}

__global__ __launch_bounds__(256) void scan_top(int* __restrict__ bsum, int nb) {
    __shared__ int sh[256];
    int t = threadIdx.x;
    int v = (t < nb) ? bsum[t] : 0;
    sh[t] = v;
    __syncthreads();
#pragma unroll
    for (int o = 1; o < 256; o <<= 1) {
        int u = (t >= o) ? sh[t - o] : 0;
        __syncthreads();
        sh[t] += u;
        __syncthreads();
    }
    if (t < nb) bsum[t] = sh[t] - v;  // exclusive
}

__global__ __launch_bounds__(256) void scan_fin(const int* __restrict__ excl,
                                                const int* __restrict__ bsum,
                                                int* __restrict__ row_ptr,
                                                int* __restrict__ fill, int n, int E) {
    int i = blockIdx.x * blockDim.x + threadIdx.x;
    if (i < n) {
        int r = excl[i] + bsum[i >> 8];
        row_ptr[i] = r;
        fill[i] = r;
    }
    if (i == 0) row_ptr[n] = E;
}

__global__ void scatter_kernel(const int* __restrict__ src, const int* __restrict__ dst,
                               int E, int* __restrict__ fill, int* __restrict__ col_src) {
    int i = blockIdx.x * blockDim.x + threadIdx.x;
    if (i < E) {
        int p = atomicAdd(&fill[dst[i]], 1);
        col_src[p] = src[i];
    }
}

// ---------------- W -> transposed, k-blocked, bf16: Wt[kb][n][kk] ----------------
__global__ void wconv_kernel(const float* __restrict__ W, int K, int N,
                             ushort* __restrict__ thi) {
    int i = blockIdx.x * blockDim.x + threadIdx.x;
    if (i >= K * N) return;
    int k = i / N, n = i - k * N;
    size_t o = ((size_t)(k >> 5) * N + n) * 32 + (k & 31);
    thi[o] = f2bf(W[i]);
}

// ---------------- MFMA GEMM (2-term bf16 split A) + fused el/er, double-buffered LDS ----------------
// A: AF32 ? fp32 [M][K] (split in-register) : pre-split hi/lo bf16 [M][K].
// W: blocked [K/32][N][32] bf16. z out bf16: H=4 packed [r][d][h]; H=1 [r][d].
// One barrier per K-step: prefetch kb+1 W-tile to regs before MFMAs, write after.
template <int N, int H, bool AF32>
__global__ __launch_bounds__(256) void gemm_mfma_eler(
    const void* __restrict__ A0, const ushort* __restrict__ Alo,
    const ushort* __restrict__ Wthi,
    ushort* __restrict__ zt, const float* __restrict__ al, const float* __restrict__ ar,
    float* __restrict__ el, float* __restrict__ er, int M, int K) {
    constexpr int NT = N / 16;
    __shared__ ushort Bh[2][N][34];  // 68B row stride (odd bank count) -> near-uniform spread
    const int t = threadIdx.x;
    const int w = t >> 6, lane = t & 63;
    const int cl = lane & 15, g = lane >> 4;
    const int bm = blockIdx.x * 64;
    const int arow = bm + 16 * w + cl;
    const bool aval = arow < M;
    const size_t abase = (size_t)arow * K;
    const float* Af = (const float*)A0;
    const ushort* Ahi = (const ushort*)A0;

    f32x4 acc[NT];
#pragma unroll
    for (int nt = 0; nt < NT; ++nt) acc[nt] = (f32x4){0.f, 0.f, 0.f, 0.f};

    const int nkb = K >> 5;
    // prologue: stage kb=0 into buffer 0
    if (t < N) {
        const float4* gs = (const float4*)(Wthi + (size_t)t * 32);
#pragma unroll
        for (int q = 0; q < 4; ++q) *(float4*)&Bh[0][t][q * 8] = gs[q];
    }
    __syncthreads();

    for (int kb = 0; kb < nkb; ++kb) {
        const int cur = kb & 1;
        // prefetch next W-tile into registers (loads issue now, consumed after MFMAs)
        float4 rn0, rn1, rn2, rn3;
        const bool pf = (kb + 1 < nkb) && (t < N);
        if (pf) {
            const float4* gs = (const float4*)(Wthi + ((size_t)(kb + 1) * N + t) * 32);
            rn0 = gs[0]; rn1 = gs[1]; rn2 = gs[2]; rn3 = gs[3];
        }
        // A fragments
        bf16x8 a_hi = {0, 0, 0, 0, 0, 0, 0, 0};
        bf16x8 a_lo = {0, 0, 0, 0, 0, 0, 0, 0};
        if (aval) {
            if (AF32) {
                float4 f0 = *(const float4*)(Af + abase + kb * 32 + g * 8);
                float4 f1 = *(const float4*)(Af + abase + kb * 32 + g * 8 + 4);
                float fv[8] = {f0.x, f0.y, f0.z, f0.w, f1.x, f1.y, f1.z, f1.w};
#pragma unroll
                for (int q = 0; q < 8; ++q) {
                    ushort hb = f2bf(fv[q]);
                    a_hi[q] = (short)hb;
                    a_lo[q] = (short)f2bf(fv[q] - bf2f(hb));
                }
            } else {
                a_hi = *(const bf16x8*)(Ahi + abase + kb * 32 + g * 8);
                a_lo = *(const bf16x8*)(Alo + abase + kb * 32 + g * 8);
            }
        }
#pragma unroll
        for (int nt = 0; nt < NT; ++nt) {
            bf16x8 b_hi = *(const bf16x8*)&Bh[cur][16 * nt + cl][g * 8];
            acc[nt] = __builtin_amdgcn_mfma_f32_16x16x32_bf16(a_hi, b_hi, acc[nt], 0, 0, 0);
            acc[nt] = __builtin_amdgcn_mfma_f32_16x16x32_bf16(a_lo, b_hi, acc[nt], 0, 0, 0);
        }
        // write prefetched tile to the other buffer
        if (pf) {
            *(float4*)&Bh[cur ^ 1][t][0]  = rn0;
            *(float4*)&Bh[cur ^ 1][t][8]  = rn1;
            *(float4*)&Bh[cur ^ 1][t][16] = rn2;
            *(float4*)&Bh[cur ^ 1][t][24] = rn3;
        }
        __syncthreads();
    }

    // z store (bf16). Lane holds C[r0+j][16nt+cl], r0 = bm+16w+4g.
    const int r0 = bm + 16 * w + 4 * g;
    if (H == 4) {
#pragma unroll
        for (int tt = 0; tt < 4; ++tt) {
#pragma unroll
            for (int j = 0; j < 4; ++j) {
                int r = r0 + j;
                if (r < M) {
                    u16x4 pv;
#pragma unroll
                    for (int h = 0; h < 4; ++h) pv[h] = f2bf(acc[4 * h + tt][j]);
                    *(u16x4*)&zt[(size_t)r * 256 + (16 * tt + cl) * 4] = pv;
                }
            }
        }
    } else {
#pragma unroll
        for (int nt = 0; nt < NT; ++nt) {
#pragma unroll
            for (int j = 0; j < 4; ++j) {
                int r = r0 + j;
                if (r < M) zt[(size_t)r * N + 16 * nt + cl] = f2bf(acc[nt][j]);
            }
        }
    }
    // fused el/er
#pragma unroll
    for (int h = 0; h < H; ++h) {
        float pl[4] = {0.f, 0.f, 0.f, 0.f};
        float pr[4] = {0.f, 0.f, 0.f, 0.f};
#pragma unroll
        for (int tt = 0; tt < 4; ++tt) {
            int nt = 4 * h + tt;
            float av = al[h * DD + 16 * tt + cl];
            float rv = ar[h * DD + 16 * tt + cl];
#pragma unroll
            for (int j = 0; j < 4; ++j) {
                pl[j] += acc[nt][j] * av;
                pr[j] += acc[nt][j] * rv;
            }
        }
#pragma unroll
        for (int j = 0; j < 4; ++j) {
#pragma unroll
            for (int o = 1; o < 16; o <<= 1) {
                pl[j] += __shfl_xor(pl[j], o);
                pr[j] += __shfl_xor(pr[j], o);
            }
        }
        if (cl == 0) {
#pragma unroll
            for (int j = 0; j < 4; ++j) {
                int r = r0 + j;
                if (r < M) {
                    el[(size_t)r * H + h] = pl[j];
                    er[(size_t)r * H + h] = pr[j];
                }
            }
        }
    }
}

// ---------------- fused attention + aggregation: one wave per dst ----------------
// phase A (lane=edge): alpha computed once per edge -> per-wave LDS
// phase B (lane=feature): acc[h] += alpha[j][h] * z[src_j]  (LDS broadcast reads)
template <int H, bool SPLIT>
__global__ __launch_bounds__(256) void agg_fused(const ushort* __restrict__ zt,
                                                 const float* __restrict__ el,
                                                 const float* __restrict__ er,
                                                 const int* __restrict__ row_ptr,
                                                 const int* __restrict__ col_src,
                                                 float* __restrict__ outf,
                                                 ushort* __restrict__ ohi,
                                                 ushort* __restrict__ olo) {
    __shared__ float alf[4][64][H];  // per-wave alpha slab
    __shared__ int als[4][64];       // per-wave src ids
    const int wid = threadIdx.x >> 6;
    const int lane = threadIdx.x & 63;
    int v = blockIdx.x * 4 + wid;
    if (v >= NN) return;
    int start = row_ptr[v], end = row_ptr[v + 1];
    int deg = end - start;
    float erd[H], acc[H];
#pragma unroll
    for (int h = 0; h < H; ++h) {
        erd[h] = er[(size_t)v * H + h];
        acc[h] = 0.f;
    }

    auto agg_chunk = [&](int cnt) {
        int j = 0;
        for (; j + 4 <= cnt; j += 4) {
            int s0 = als[wid][j + 0], s1 = als[wid][j + 1];
            int s2 = als[wid][j + 2], s3 = als[wid][j + 3];
            if (H == 4) {
                f32x4 a0 = *(const f32x4*)&alf[wid][j + 0][0];
                f32x4 a1 = *(const f32x4*)&alf[wid][j + 1][0];
                f32x4 a2 = *(const f32x4*)&alf[wid][j + 2][0];
                f32x4 a3 = *(const f32x4*)&alf[wid][j + 3][0];
                u16x4 z0 = *(const u16x4*)&zt[(size_t)s0 * 256 + lane * 4];
                u16x4 z1 = *(const u16x4*)&zt[(size_t)s1 * 256 + lane * 4];
                u16x4 z2 = *(const u16x4*)&zt[(size_t)s2 * 256 + lane * 4];
                u16x4 z3 = *(const u16x4*)&zt[(size_t)s3 * 256 + lane * 4];
#pragma unroll
                for (int h = 0; h < 4; ++h) {
                    acc[h] += a0[h] * bf2f(z0[h]);
                    acc[h] += a1[h] * bf2f(z1[h]);
                    acc[h] += a2[h] * bf2f(z2[h]);
                    acc[h] += a3[h] * bf2f(z3[h]);
                }
            } else {
                float a0 = alf[wid][j + 0][0], a1 = alf[wid][j + 1][0];
                float a2 = alf[wid][j + 2][0], a3 = alf[wid][j + 3][0];
                ushort z0 = zt[(size_t)s0 * 64 + lane];
                ushort z1 = zt[(size_t)s1 * 64 + lane];
                ushort z2 = zt[(size_t)s2 * 64 + lane];
                ushort z3 = zt[(size_t)s3 * 64 + lane];
                acc[0] += a0 * bf2f(z0);
                acc[0] += a1 * bf2f(z1);
                acc[0] += a2 * bf2f(z2);
                acc[0] += a3 * bf2f(z3);
            }
        }
        for (; j < cnt; ++j) {
            int s = als[wid][j];
            if (H == 4) {
                f32x4 a = *(const f32x4*)&alf[wid][j][0];
                u16x4 z = *(const u16x4*)&zt[(size_t)s * 256 + lane * 4];
#pragma unroll
                for (int h = 0; h < 4; ++h) acc[h] += a[h] * bf2f(z[h]);
            } else {
                acc[0] += alf[wid][j][0] * bf2f(zt[(size_t)s * 64 + lane]);
            }
        }
    };

    if (deg <= 64) {
        bool valid = lane < deg;
        int s = col_src[valid ? start + lane : start];
        als[wid][lane] = s;
        float e[H];
        if (H == 4) {
            f32x4 ev = *(const f32x4*)&el[(size_t)s * 4];
#pragma unroll
            for (int h = 0; h < 4; ++h) {
                float x = ev[h] + erd[h];
                x = (x >= 0.f) ? x : NEG_SLOPE * x;
                e[h] = valid ? x : -1e30f;
            }
        } else {
            float x = el[s] + erd[0];
            x = (x >= 0.f) ? x : NEG_SLOPE * x;
            e[0] = valid ? x : -1e30f;
        }
#pragma unroll
        for (int h = 0; h < H; ++h) {
            float m = wave_max(e[h]);
            float ex = valid ? __expf(e[h] - m) : 0.f;
            float den = wave_sum(ex);
            alf[wid][lane][h] = ex * (1.f / den);
        }
        __builtin_amdgcn_wave_barrier();
        agg_chunk(deg);
    } else {
        float m[H];
#pragma unroll
        for (int h = 0; h < H; ++h) m[h] = -1e30f;
        for (int base = start; base < end; base += 64) {
            int i = base + lane;
            bool valid = i < end;
            int s = col_src[valid ? i : start];
#pragma unroll
            for (int h = 0; h < H; ++h) {
                float x = el[(size_t)s * H + h] + erd[h];
                x = (x >= 0.f) ? x : NEG_SLOPE * x;
                m[h] = fmaxf(m[h], valid ? x : -1e30f);
            }
        }
        float den[H];
#pragma unroll
        for (int h = 0; h < H; ++h) {
            m[h] = wave_max(m[h]);
            den[h] = 0.f;
        }
        for (int base = start; base < end; base += 64) {
            int i = base + lane;
            bool valid = i < end;
            int s = col_src[valid ? i : start];
#pragma unroll
            for (int h = 0; h < H; ++h) {
                float x = el[(size_t)s * H + h] + erd[h];
                x = (x >= 0.f) ? x : NEG_SLOPE * x;
                den[h] += valid ? __expf(x - m[h]) : 0.f;
            }
        }
        float inv[H];
#pragma unroll
        for (int h = 0; h < H; ++h) inv[h] = 1.f / wave_sum(den[h]);
        for (int base = start; base < end; base += 64) {
            int i = base + lane;
            bool valid = i < end;
            int s = col_src[valid ? i : start];
            als[wid][lane] = s;
#pragma unroll
            for (int h = 0; h < H; ++h) {
                float x = el[(size_t)s * H + h] + erd[h];
                x = (x >= 0.f) ? x : NEG_SLOPE * x;
                alf[wid][lane][h] = valid ? __expf(x - m[h]) * inv[h] : 0.f;
            }
            __builtin_amdgcn_wave_barrier();
            int cnt = min(64, end - base);
            agg_chunk(cnt);
            __builtin_amdgcn_wave_barrier();
        }
    }

#pragma unroll
    for (int h = 0; h < H; ++h) {
        float r = acc[h];
        r = (r > 0.f) ? r : 0.f;  // fused ReLU
        size_t idx = (size_t)v * H * DD + h * DD + lane;
        if (SPLIT) {
            ushort hb = f2bf(r);
            ohi[idx] = hb;
            olo[idx] = f2bf(r - bf2f(hb));
        } else {
            outf[idx] = r;
        }
    }
}

// ---------------- pooling ----------------
__device__ inline int lower_bound_dev(const int* a, int n, int v) {
    int lo = 0, hi = n;
    while (lo < hi) {
        int mid = (lo + hi) >> 1;
        if (a[mid] < v) lo = mid + 1; else hi = mid;
    }
    return lo;
}

__global__ __launch_bounds__(256) void pool_kernel(const float* __restrict__ x,
                                                   const int* __restrict__ gid,
                                                   float* __restrict__ pooled,
                                                   float* __restrict__ gcnt) {
    int g = blockIdx.x;
    int start = lower_bound_dev(gid, NN, g);
    int end = lower_bound_dev(gid, NN, g + 1);
    int lane = threadIdx.x & 63;
    int w = threadIdx.x >> 6;
    float acc = 0.f;
    for (int i = start + w; i < end; i += 4) acc += x[(size_t)i * DD + lane];
    __shared__ float red[4][DD];
    red[w][lane] = acc;
    __syncthreads();
    if (w == 0) {
        float s = red[0][lane] + red[1][lane] + red[2][lane] + red[3][lane];
        pooled[g * DD + lane] = s;
        if (lane == 0) gcnt[g] = (float)(end - start);
    }
}

// ---------------- head ----------------
__global__ __launch_bounds__(64) void head_kernel(const float* __restrict__ pooled,
                                                  const float* __restrict__ gcnt,
                                                  const float* __restrict__ fc1w,
                                                  const float* __restrict__ fc1b,
                                                  const float* __restrict__ fc2w,
                                                  const float* __restrict__ fc2b,
                                                  float* __restrict__ out) {
    __shared__ float P[GG][DD + 1];
    __shared__ float Y1[GG][DD + 1];
    int g = threadIdx.x;
    float c = fmaxf(gcnt[g], 1.0f);
    for (int k = 0; k < DD; ++k) P[g][k] = pooled[g * DD + k] / c;
    __syncthreads();
    for (int j = 0; j < DD; ++j) {
        float s = fc1b[j];
        for (int k = 0; k < DD; ++k) s += P[g][k] * fc1w[k * DD + j];
        Y1[g][j] = (s > 0.f) ? s : expm1f(s);
    }
    __syncthreads();
    float y2[CC];
    for (int c2 = 0; c2 < CC; ++c2) {
        float s = fc2b[c2];
        for (int j = 0; j < DD; ++j) s += Y1[g][j] * fc2w[j * CC + c2];
        y2[c2] = s;
    }
    for (int c2 = 0; c2 < CC; ++c2) {
        float m = y2[c2];
#pragma unroll
        for (int o = 32; o > 0; o >>= 1) m = fmaxf(m, __shfl_xor(m, o));
        float sexp = __expf(y2[c2] - m);
#pragma unroll
        for (int o = 32; o > 0; o >>= 1) sexp += __shfl_xor(sexp, o);
        out[g * CC + c2] = y2[c2] - m - logf(sexp);
    }
}

// ---------------- launcher ----------------
extern "C" void kernel_launch(void* const* d_in, const int* in_sizes, int n_in,
                              void* d_out, int out_size, void* d_ws, size_t ws_size,
                              hipStream_t stream) {
    const float* h    = (const float*)d_in[0];
    const int* src    = (const int*)d_in[1];
    const int* dst    = (const int*)d_in[2];
    const int* gid    = (const int*)d_in[3];
    const float* W0   = (const float*)d_in[4];
    const float* al0  = (const float*)d_in[5];
    const float* ar0  = (const float*)d_in[6];
    const float* W1   = (const float*)d_in[7];
    const float* al1  = (const float*)d_in[8];
    const float* ar1  = (const float*)d_in[9];
    const float* W2   = (const float*)d_in[10];
    const float* al2  = (const float*)d_in[11];
    const float* ar2  = (const float*)d_in[12];
    const float* W3   = (const float*)d_in[13];
    const float* al3  = (const float*)d_in[14];
    const float* ar3  = (const float*)d_in[15];
    const float* fc1w = (const float*)d_in[16];
    const float* fc1b = (const float*)d_in[17];
    const float* fc2w = (const float*)d_in[18];
    const float* fc2b = (const float*)d_in[19];
    const int E = in_sizes[1];

    char* wsb = (char*)d_ws;
    size_t off = 0;
    auto alloc = [&](size_t bytes) -> void* {
        void* p = wsb + off;
        off = (off + bytes + 255) & ~(size_t)255;
        return p;
    };
    ushort* zt      = (ushort*)alloc((size_t)NN * 256 * 2);  // z bf16, packed [v][d][h] (H=4) / [v][d] (H=1)
    ushort* Ahi     = (ushort*)alloc((size_t)NN * 256 * 2);
    ushort* Alo     = (ushort*)alloc((size_t)NN * 256 * 2);
    float*  bufA    = (float*)alloc((size_t)NN * DD * 4);
    float*  el      = (float*)alloc((size_t)NN * HH * 4);
    float*  er      = (float*)alloc((size_t)NN * HH * 4);
    int*    counts  = (int*)alloc((size_t)NN * 4);
    int*    row_ptr = (int*)alloc((size_t)(NN + 1) * 4);
    int*    fill    = (int*)alloc((size_t)NN * 4);
    int*    excl    = (int*)alloc((size_t)NN * 4);
    int*    bsum    = (int*)alloc((size_t)256 * 4);
    int*    col_src = (int*)alloc((size_t)E * 4);
    float*  pooled  = (float*)alloc((size_t)GG * DD * 4);
    float*  gcnt    = (float*)alloc((size_t)GG * 4);
    ushort* w0h     = (ushort*)alloc((size_t)IN_F * 256 * 2);
    ushort* w1h     = (ushort*)alloc((size_t)256 * 256 * 2);
    ushort* w2h     = (ushort*)alloc((size_t)256 * 256 * 2);
    ushort* w3h     = (ushort*)alloc((size_t)256 * 64 * 2);

    // ---- CSR build ----
    hipMemsetAsync(counts, 0, (size_t)NN * 4, stream);
    int eg = (E + 255) / 256;
    const int nScanBlk = (NN + 255) / 256;  // 196
    hist_kernel<<<eg, 256, 0, stream>>>(dst, E, counts);
    scan_blk<<<nScanBlk, 256, 0, stream>>>(counts, excl, bsum, NN);
    scan_top<<<1, 256, 0, stream>>>(bsum, nScanBlk);
    scan_fin<<<nScanBlk, 256, 0, stream>>>(excl, bsum, row_ptr, fill, NN, E);
    scatter_kernel<<<eg, 256, 0, stream>>>(src, dst, E, fill, col_src);

    // ---- weight conversions (bf16, transposed k-blocked) ----
    wconv_kernel<<<(IN_F * 256 + 255) / 256, 256, 0, stream>>>(W0, IN_F, 256, w0h);
    wconv_kernel<<<(256 * 256 + 255) / 256, 256, 0, stream>>>(W1, 256, 256, w1h);
    wconv_kernel<<<(256 * 256 + 255) / 256, 256, 0, stream>>>(W2, 256, 256, w2h);
    wconv_kernel<<<(256 * 64 + 255) / 256, 256, 0, stream>>>(W3, 256, 64, w3h);

    const int gemmGrid = (NN + 63) / 64;  // 782
    const int waveBlocks = (NN + 3) / 4;  // 12500

    // ---- layer 0 (K=128, N=256, H=4): A = h fp32, split in-register ----
    gemm_mfma_eler<256, 4, true><<<gemmGrid, 256, 0, stream>>>(h, nullptr, w0h, zt, al0, ar0, el, er, NN, IN_F);
    agg_fused<4, true><<<waveBlocks, 256, 0, stream>>>(zt, el, er, row_ptr, col_src, nullptr, Ahi, Alo);

    // ---- layer 1 ----
    gemm_mfma_eler<256, 4, false><<<gemmGrid, 256, 0, stream>>>(Ahi, Alo, w1h, zt, al1, ar1, el, er, NN, 256);
    agg_fused<4, true><<<waveBlocks, 256, 0, stream>>>(zt, el, er, row_ptr, col_src, nullptr, Ahi, Alo);

    // ---- layer 2 ----
    gemm_mfma_eler<256, 4, false><<<gemmGrid, 256, 0, stream>>>(Ahi, Alo, w2h, zt, al2, ar2, el, er, NN, 256);
    agg_fused<4, true><<<waveBlocks, 256, 0, stream>>>(zt, el, er, row_ptr, col_src, nullptr, Ahi, Alo);

    // ---- layer 3 (K=256, N=64, H=1) ----
    gemm_mfma_eler<64, 1, false><<<gemmGrid, 256, 0, stream>>>(Ahi, Alo, w3h, zt, al3, ar3, el, er, NN, 256);
    agg_fused<1, false><<<waveBlocks, 256, 0, stream>>>(zt, el, er, row_ptr, col_src, bufA, nullptr, nullptr);

    // ---- pooling + head ----
    pool_kernel<<<GG, 256, 0, stream>>>(bufA, gid, pooled, gcnt);
    head_kernel<<<1, 64, 0, stream>>>(pooled, gcnt, fc1w, fc1b, fc2w, fc2b, (float*)d_out);
}

// Round 12
// 604.510 us; speedup vs baseline: 1.2959x; 1.0166x over previous
//
#include <hip/hip_runtime.h>
#include <hip/hip_bf16.h>
#include <math.h>

#define NN 50000
#define IN_F 128
#define DD 64
#define HH 4
#define CC 10
#define GG 64
#define NEG_SLOPE 0.2f

typedef __attribute__((ext_vector_type(8))) short bf16x8;
typedef __attribute__((ext_vector_type(4))) float f32x4;
typedef __attribute__((ext_vector_type(4))) unsigned short u16x4;

__device__ inline ushort f2bf(float f) {
    unsigned u = __float_as_uint(f);
    unsigned r = (u + 0x7fffu + ((u >> 16) & 1u)) >> 16;
    return (ushort)r;
}
__device__ inline float bf2f(ushort b) { return __uint_as_float(((unsigned)b) << 16); }

// ---------------- wave helpers ----------------
__device__ inline float wave_max(float v) {
#pragma unroll
    for (int o = 32; o > 0; o >>= 1) v = fmaxf(v, __shfl_xor(v, o));
    return v;
}
__device__ inline float wave_sum(float v) {
#pragma unroll
    for (int o = 32; o > 0; o >>= 1) v += __shfl_xor(v, o);
    return v;
}

// ---------------- CSR build ----------------
__global__ void hist_kernel(const int* __restrict__ dst, int E, int* __restrict__ counts) {
    int i = blockIdx.x * blockDim.x + threadIdx.x;
    if (i < E) atomicAdd(&counts[dst[i]], 1);
}

__global__ __launch_bounds__(256) void scan_blk(const int* __restrict__ counts,
                                                int* __restrict__ excl,
                                                int* __restrict__ bsum, int n) {
    __shared__ int sh[256];
    int t = threadIdx.x;
    int i = blockIdx.x * 256 + t;
    int v = (i < n) ? counts[i] : 0;
    sh[t] = v;
    __syncthreads();
#pragma unroll
    for (int o = 1; o < 256; o <<= 1) {
        int u = (t >= o) ? sh[t - o] : 0;
        __syncthreads();
        sh[t] += u;
        __syncthreads();
    }
    if (i < n) excl[i] = sh[t] - v;
    if (t == 255) bsum[blockIdx.x] = sh[255];
}

__global__ __launch_bounds__(256) void scan_top(int* __restrict__ bsum, int nb) {
    __shared__ int sh[256];
    int t = threadIdx.x;
    int v = (t < nb) ? bsum[t] : 0;
    sh[t] = v;
    __syncthreads();
#pragma unroll
    for (int o = 1; o < 256; o <<= 1) {
        int u = (t >= o) ? sh[t - o] : 0;
        __syncthreads();
        sh[t] += u;
        __syncthreads();
    }
    if (t < nb) bsum[t] = sh[t] - v;  // exclusive
}

__global__ __launch_bounds__(256) void scan_fin(const int* __restrict__ excl,
                                                const int* __restrict__ bsum,
                                                int* __restrict__ row_ptr,
                                                int* __restrict__ fill, int n, int E) {
    int i = blockIdx.x * blockDim.x + threadIdx.x;
    if (i < n) {
        int r = excl[i] + bsum[i >> 8];
        row_ptr[i] = r;
        fill[i] = r;
    }
    if (i == 0) row_ptr[n] = E;
}

__global__ void scatter_kernel(const int* __restrict__ src, const int* __restrict__ dst,
                               int E, int* __restrict__ fill, int* __restrict__ col_src) {
    int i = blockIdx.x * blockDim.x + threadIdx.x;
    if (i < E) {
        int p = atomicAdd(&fill[dst[i]], 1);
        col_src[p] = src[i];
    }
}

// ---------------- W -> transposed, k-blocked, bf16: Wt[kb][n][kk] ----------------
__global__ void wconv_kernel(const float* __restrict__ W, int K, int N,
                             ushort* __restrict__ thi) {
    int i = blockIdx.x * blockDim.x + threadIdx.x;
    if (i >= K * N) return;
    int k = i / N, n = i - k * N;
    size_t o = ((size_t)(k >> 5) * N + n) * 32 + (k & 31);
    thi[o] = f2bf(W[i]);
}

// ---------------- MFMA GEMM (bf16) + fused el/er, full double-buffer (A regs + W LDS) ----------------
// A: AF32 ? fp32 [M][K] (convert in-register) : bf16 [M][K].
// W: blocked [K/32][N][32] bf16. z out bf16: H=4 packed [r][d][h]; H=1 [r][d].
// One barrier per K-step; A(kb+1) and W(kb+1) both prefetched during MFMAs.
template <int N, int H, bool AF32>
__global__ __launch_bounds__(256) void gemm_mfma_eler(
    const void* __restrict__ A0,
    const ushort* __restrict__ Wthi,
    ushort* __restrict__ zt, const float* __restrict__ al, const float* __restrict__ ar,
    float* __restrict__ el, float* __restrict__ er, int M, int K) {
    constexpr int NT = N / 16;
    __shared__ ushort Bh[2][N][34];  // 68B row stride (odd bank count) -> near-uniform spread
    const int t = threadIdx.x;
    const int w = t >> 6, lane = t & 63;
    const int cl = lane & 15, g = lane >> 4;
    const int bm = blockIdx.x * 64;
    const int arow = bm + 16 * w + cl;
    const bool aval = arow < M;
    const size_t abase = (size_t)arow * K;
    const float* Af = (const float*)A0;
    const ushort* Abf = (const ushort*)A0;

    f32x4 acc[NT];
#pragma unroll
    for (int nt = 0; nt < NT; ++nt) acc[nt] = (f32x4){0.f, 0.f, 0.f, 0.f};

    const int nkb = K >> 5;

    // raw A-prefetch registers (kb=0)
    float4 fa0 = {0, 0, 0, 0}, fa1 = {0, 0, 0, 0};
    bf16x8 araw = {0, 0, 0, 0, 0, 0, 0, 0};
    if (aval) {
        if (AF32) {
            fa0 = *(const float4*)(Af + abase + g * 8);
            fa1 = *(const float4*)(Af + abase + g * 8 + 4);
        } else {
            araw = *(const bf16x8*)(Abf + abase + g * 8);
        }
    }
    // prologue: stage W kb=0 into buffer 0
    if (t < N) {
        const float4* gs = (const float4*)(Wthi + (size_t)t * 32);
#pragma unroll
        for (int q = 0; q < 4; ++q) *(float4*)&Bh[0][t][q * 8] = gs[q];
    }
    __syncthreads();

    for (int kb = 0; kb < nkb; ++kb) {
        const int cur = kb & 1;
        // materialize current A fragment (VALU only; raw data already resident)
        bf16x8 a_cur;
        if (AF32) {
            float fv[8] = {fa0.x, fa0.y, fa0.z, fa0.w, fa1.x, fa1.y, fa1.z, fa1.w};
#pragma unroll
            for (int q = 0; q < 8; ++q) a_cur[q] = (short)f2bf(fv[q]);
        } else {
            a_cur = araw;
        }
        // prefetch next K-step operands (consumed after the MFMA block)
        float4 rn0, rn1, rn2, rn3;
        const bool pf = (kb + 1 < nkb);
        if (pf && t < N) {
            const float4* gs = (const float4*)(Wthi + ((size_t)(kb + 1) * N + t) * 32);
            rn0 = gs[0]; rn1 = gs[1]; rn2 = gs[2]; rn3 = gs[3];
        }
        if (pf && aval) {
            if (AF32) {
                fa0 = *(const float4*)(Af + abase + (kb + 1) * 32 + g * 8);
                fa1 = *(const float4*)(Af + abase + (kb + 1) * 32 + g * 8 + 4);
            } else {
                araw = *(const bf16x8*)(Abf + abase + (kb + 1) * 32 + g * 8);
            }
        }
#pragma unroll
        for (int nt = 0; nt < NT; ++nt) {
            bf16x8 b_hi = *(const bf16x8*)&Bh[cur][16 * nt + cl][g * 8];
            acc[nt] = __builtin_amdgcn_mfma_f32_16x16x32_bf16(a_cur, b_hi, acc[nt], 0, 0, 0);
        }
        // write prefetched W tile to the other buffer
        if (pf && t < N) {
            *(float4*)&Bh[cur ^ 1][t][0]  = rn0;
            *(float4*)&Bh[cur ^ 1][t][8]  = rn1;
            *(float4*)&Bh[cur ^ 1][t][16] = rn2;
            *(float4*)&Bh[cur ^ 1][t][24] = rn3;
        }
        __syncthreads();
    }

    // z store (bf16). Lane holds C[r0+j][16nt+cl], r0 = bm+16w+4g.
    const int r0 = bm + 16 * w + 4 * g;
    if (H == 4) {
#pragma unroll
        for (int tt = 0; tt < 4; ++tt) {
#pragma unroll
            for (int j = 0; j < 4; ++j) {
                int r = r0 + j;
                if (r < M) {
                    u16x4 pv;
#pragma unroll
                    for (int h = 0; h < 4; ++h) pv[h] = f2bf(acc[4 * h + tt][j]);
                    *(u16x4*)&zt[(size_t)r * 256 + (16 * tt + cl) * 4] = pv;
                }
            }
        }
    } else {
#pragma unroll
        for (int nt = 0; nt < NT; ++nt) {
#pragma unroll
            for (int j = 0; j < 4; ++j) {
                int r = r0 + j;
                if (r < M) zt[(size_t)r * N + 16 * nt + cl] = f2bf(acc[nt][j]);
            }
        }
    }
    // fused el/er
#pragma unroll
    for (int h = 0; h < H; ++h) {
        float pl[4] = {0.f, 0.f, 0.f, 0.f};
        float pr[4] = {0.f, 0.f, 0.f, 0.f};
#pragma unroll
        for (int tt = 0; tt < 4; ++tt) {
            int nt = 4 * h + tt;
            float av = al[h * DD + 16 * tt + cl];
            float rv = ar[h * DD + 16 * tt + cl];
#pragma unroll
            for (int j = 0; j < 4; ++j) {
                pl[j] += acc[nt][j] * av;
                pr[j] += acc[nt][j] * rv;
            }
        }
#pragma unroll
        for (int j = 0; j < 4; ++j) {
#pragma unroll
            for (int o = 1; o < 16; o <<= 1) {
                pl[j] += __shfl_xor(pl[j], o);
                pr[j] += __shfl_xor(pr[j], o);
            }
        }
        if (cl == 0) {
#pragma unroll
            for (int j = 0; j < 4; ++j) {
                int r = r0 + j;
                if (r < M) {
                    el[(size_t)r * H + h] = pl[j];
                    er[(size_t)r * H + h] = pr[j];
                }
            }
        }
    }
}

// ---------------- fused attention + aggregation: one wave per dst ----------------
// phase A (lane=edge): alpha computed once per edge -> per-wave LDS
// phase B (lane=feature): acc[h] += alpha[j][h] * z[src_j]  (LDS broadcast reads)
// OUTBF: write bf16 [v][h*64+lane] (feeds next GEMM); else fp32 (layer 3, feeds pool)
template <int H, bool OUTBF>
__global__ __launch_bounds__(256) void agg_fused(const ushort* __restrict__ zt,
                                                 const float* __restrict__ el,
                                                 const float* __restrict__ er,
                                                 const int* __restrict__ row_ptr,
                                                 const int* __restrict__ col_src,
                                                 float* __restrict__ outf,
                                                 ushort* __restrict__ obf) {
    __shared__ float alf[4][64][H];  // per-wave alpha slab
    __shared__ int als[4][64];       // per-wave src ids
    const int wid = threadIdx.x >> 6;
    const int lane = threadIdx.x & 63;
    int v = blockIdx.x * 4 + wid;
    if (v >= NN) return;
    int start = row_ptr[v], end = row_ptr[v + 1];
    int deg = end - start;
    float erd[H], acc[H];
#pragma unroll
    for (int h = 0; h < H; ++h) {
        erd[h] = er[(size_t)v * H + h];
        acc[h] = 0.f;
    }

    auto agg_chunk = [&](int cnt) {
        int j = 0;
        for (; j + 4 <= cnt; j += 4) {
            int s0 = als[wid][j + 0], s1 = als[wid][j + 1];
            int s2 = als[wid][j + 2], s3 = als[wid][j + 3];
            if (H == 4) {
                f32x4 a0 = *(const f32x4*)&alf[wid][j + 0][0];
                f32x4 a1 = *(const f32x4*)&alf[wid][j + 1][0];
                f32x4 a2 = *(const f32x4*)&alf[wid][j + 2][0];
                f32x4 a3 = *(const f32x4*)&alf[wid][j + 3][0];
                u16x4 z0 = *(const u16x4*)&zt[(size_t)s0 * 256 + lane * 4];
                u16x4 z1 = *(const u16x4*)&zt[(size_t)s1 * 256 + lane * 4];
                u16x4 z2 = *(const u16x4*)&zt[(size_t)s2 * 256 + lane * 4];
                u16x4 z3 = *(const u16x4*)&zt[(size_t)s3 * 256 + lane * 4];
#pragma unroll
                for (int h = 0; h < 4; ++h) {
                    acc[h] += a0[h] * bf2f(z0[h]);
                    acc[h] += a1[h] * bf2f(z1[h]);
                    acc[h] += a2[h] * bf2f(z2[h]);
                    acc[h] += a3[h] * bf2f(z3[h]);
                }
            } else {
                float a0 = alf[wid][j + 0][0], a1 = alf[wid][j + 1][0];
                float a2 = alf[wid][j + 2][0], a3 = alf[wid][j + 3][0];
                ushort z0 = zt[(size_t)s0 * 64 + lane];
                ushort z1 = zt[(size_t)s1 * 64 + lane];
                ushort z2 = zt[(size_t)s2 * 64 + lane];
                ushort z3 = zt[(size_t)s3 * 64 + lane];
                acc[0] += a0 * bf2f(z0);
                acc[0] += a1 * bf2f(z1);
                acc[0] += a2 * bf2f(z2);
                acc[0] += a3 * bf2f(z3);
            }
        }
        for (; j < cnt; ++j) {
            int s = als[wid][j];
            if (H == 4) {
                f32x4 a = *(const f32x4*)&alf[wid][j][0];
                u16x4 z = *(const u16x4*)&zt[(size_t)s * 256 + lane * 4];
#pragma unroll
                for (int h = 0; h < 4; ++h) acc[h] += a[h] * bf2f(z[h]);
            } else {
                acc[0] += alf[wid][j][0] * bf2f(zt[(size_t)s * 64 + lane]);
            }
        }
    };

    if (deg <= 64) {
        bool valid = lane < deg;
        int s = col_src[valid ? start + lane : start];
        als[wid][lane] = s;
        float e[H];
        if (H == 4) {
            f32x4 ev = *(const f32x4*)&el[(size_t)s * 4];
#pragma unroll
            for (int h = 0; h < 4; ++h) {
                float x = ev[h] + erd[h];
                x = (x >= 0.f) ? x : NEG_SLOPE * x;
                e[h] = valid ? x : -1e30f;
            }
        } else {
            float x = el[s] + erd[0];
            x = (x >= 0.f) ? x : NEG_SLOPE * x;
            e[0] = valid ? x : -1e30f;
        }
#pragma unroll
        for (int h = 0; h < H; ++h) {
            float m = wave_max(e[h]);
            float ex = valid ? __expf(e[h] - m) : 0.f;
            float den = wave_sum(ex);
            alf[wid][lane][h] = ex * (1.f / den);
        }
        __builtin_amdgcn_wave_barrier();
        agg_chunk(deg);
    } else {
        float m[H];
#pragma unroll
        for (int h = 0; h < H; ++h) m[h] = -1e30f;
        for (int base = start; base < end; base += 64) {
            int i = base + lane;
            bool valid = i < end;
            int s = col_src[valid ? i : start];
#pragma unroll
            for (int h = 0; h < H; ++h) {
                float x = el[(size_t)s * H + h] + erd[h];
                x = (x >= 0.f) ? x : NEG_SLOPE * x;
                m[h] = fmaxf(m[h], valid ? x : -1e30f);
            }
        }
        float den[H];
#pragma unroll
        for (int h = 0; h < H; ++h) {
            m[h] = wave_max(m[h]);
            den[h] = 0.f;
        }
        for (int base = start; base < end; base += 64) {
            int i = base + lane;
            bool valid = i < end;
            int s = col_src[valid ? i : start];
#pragma unroll
            for (int h = 0; h < H; ++h) {
                float x = el[(size_t)s * H + h] + erd[h];
                x = (x >= 0.f) ? x : NEG_SLOPE * x;
                den[h] += valid ? __expf(x - m[h]) : 0.f;
            }
        }
        float inv[H];
#pragma unroll
        for (int h = 0; h < H; ++h) inv[h] = 1.f / wave_sum(den[h]);
        for (int base = start; base < end; base += 64) {
            int i = base + lane;
            bool valid = i < end;
            int s = col_src[valid ? i : start];
            als[wid][lane] = s;
#pragma unroll
            for (int h = 0; h < H; ++h) {
                float x = el[(size_t)s * H + h] + erd[h];
                x = (x >= 0.f) ? x : NEG_SLOPE * x;
                alf[wid][lane][h] = valid ? __expf(x - m[h]) * inv[h] : 0.f;
            }
            __builtin_amdgcn_wave_barrier();
            int cnt = min(64, end - base);
            agg_chunk(cnt);
            __builtin_amdgcn_wave_barrier();
        }
    }

#pragma unroll
    for (int h = 0; h < H; ++h) {
        float r = acc[h];
        r = (r > 0.f) ? r : 0.f;  // fused ReLU
        size_t idx = (size_t)v * H * DD + h * DD + lane;
        if (OUTBF) {
            obf[idx] = f2bf(r);
        } else {
            outf[idx] = r;
        }
    }
}

// ---------------- pooling ----------------
__device__ inline int lower_bound_dev(const int* a, int n, int v) {
    int lo = 0, hi = n;
    while (lo < hi) {
        int mid = (lo + hi) >> 1;
        if (a[mid] < v) lo = mid + 1; else hi = mid;
    }
    return lo;
}

__global__ __launch_bounds__(256) void pool_kernel(const float* __restrict__ x,
                                                   const int* __restrict__ gid,
                                                   float* __restrict__ pooled,
                                                   float* __restrict__ gcnt) {
    int g = blockIdx.x;
    int start = lower_bound_dev(gid, NN, g);
    int end = lower_bound_dev(gid, NN, g + 1);
    int lane = threadIdx.x & 63;
    int w = threadIdx.x >> 6;
    float acc = 0.f;
    for (int i = start + w; i < end; i += 4) acc += x[(size_t)i * DD + lane];
    __shared__ float red[4][DD];
    red[w][lane] = acc;
    __syncthreads();
    if (w == 0) {
        float s = red[0][lane] + red[1][lane] + red[2][lane] + red[3][lane];
        pooled[g * DD + lane] = s;
        if (lane == 0) gcnt[g] = (float)(end - start);
    }
}

// ---------------- head ----------------
__global__ __launch_bounds__(64) void head_kernel(const float* __restrict__ pooled,
                                                  const float* __restrict__ gcnt,
                                                  const float* __restrict__ fc1w,
                                                  const float* __restrict__ fc1b,
                                                  const float* __restrict__ fc2w,
                                                  const float* __restrict__ fc2b,
                                                  float* __restrict__ out) {
    __shared__ float P[GG][DD + 1];
    __shared__ float Y1[GG][DD + 1];
    int g = threadIdx.x;
    float c = fmaxf(gcnt[g], 1.0f);
    for (int k = 0; k < DD; ++k) P[g][k] = pooled[g * DD + k] / c;
    __syncthreads();
    for (int j = 0; j < DD; ++j) {
        float s = fc1b[j];
        for (int k = 0; k < DD; ++k) s += P[g][k] * fc1w[k * DD + j];
        Y1[g][j] = (s > 0.f) ? s : expm1f(s);
    }
    __syncthreads();
    float y2[CC];
    for (int c2 = 0; c2 < CC; ++c2) {
        float s = fc2b[c2];
        for (int j = 0; j < DD; ++j) s += Y1[g][j] * fc2w[j * CC + c2];
        y2[c2] = s;
    }
    for (int c2 = 0; c2 < CC; ++c2) {
        float m = y2[c2];
#pragma unroll
        for (int o = 32; o > 0; o >>= 1) m = fmaxf(m, __shfl_xor(m, o));
        float sexp = __expf(y2[c2] - m);
#pragma unroll
        for (int o = 32; o > 0; o >>= 1) sexp += __shfl_xor(sexp, o);
        out[g * CC + c2] = y2[c2] - m - logf(sexp);
    }
}

// ---------------- launcher ----------------
extern "C" void kernel_launch(void* const* d_in, const int* in_sizes, int n_in,
                              void* d_out, int out_size, void* d_ws, size_t ws_size,
                              hipStream_t stream) {
    const float* h    = (const float*)d_in[0];
    const int* src    = (const int*)d_in[1];
    const int* dst    = (const int*)d_in[2];
    const int* gid    = (const int*)d_in[3];
    const float* W0   = (const float*)d_in[4];
    const float* al0  = (const float*)d_in[5];
    const float* ar0  = (const float*)d_in[6];
    const float* W1   = (const float*)d_in[7];
    const float* al1  = (const float*)d_in[8];
    const float* ar1  = (const float*)d_in[9];
    const float* W2   = (const float*)d_in[10];
    const float* al2  = (const float*)d_in[11];
    const float* ar2  = (const float*)d_in[12];
    const float* W3   = (const float*)d_in[13];
    const float* al3  = (const float*)d_in[14];
    const float* ar3  = (const float*)d_in[15];
    const float* fc1w = (const float*)d_in[16];
    const float* fc1b = (const float*)d_in[17];
    const float* fc2w = (const float*)d_in[18];
    const float* fc2b = (const float*)d_in[19];
    const int E = in_sizes[1];

    char* wsb = (char*)d_ws;
    size_t off = 0;
    auto alloc = [&](size_t bytes) -> void* {
        void* p = wsb + off;
        off = (off + bytes + 255) & ~(size_t)255;
        return p;
    };
    ushort* zt      = (ushort*)alloc((size_t)NN * 256 * 2);  // z bf16, packed [v][d][h] (H=4) / [v][d] (H=1)
    ushort* Abf     = (ushort*)alloc((size_t)NN * 256 * 2);  // GEMM A input (bf16), layers 1-3
    float*  bufA    = (float*)alloc((size_t)NN * DD * 4);    // layer-3 output (fp32, for pool)
    float*  el      = (float*)alloc((size_t)NN * HH * 4);
    float*  er      = (float*)alloc((size_t)NN * HH * 4);
    int*    counts  = (int*)alloc((size_t)NN * 4);
    int*    row_ptr = (int*)alloc((size_t)(NN + 1) * 4);
    int*    fill    = (int*)alloc((size_t)NN * 4);
    int*    excl    = (int*)alloc((size_t)NN * 4);
    int*    bsum    = (int*)alloc((size_t)256 * 4);
    int*    col_src = (int*)alloc((size_t)E * 4);
    float*  pooled  = (float*)alloc((size_t)GG * DD * 4);
    float*  gcnt    = (float*)alloc((size_t)GG * 4);
    ushort* w0h     = (ushort*)alloc((size_t)IN_F * 256 * 2);
    ushort* w1h     = (ushort*)alloc((size_t)256 * 256 * 2);
    ushort* w2h     = (ushort*)alloc((size_t)256 * 256 * 2);
    ushort* w3h     = (ushort*)alloc((size_t)256 * 64 * 2);

    // ---- CSR build ----
    hipMemsetAsync(counts, 0, (size_t)NN * 4, stream);
    int eg = (E + 255) / 256;
    const int nScanBlk = (NN + 255) / 256;  // 196
    hist_kernel<<<eg, 256, 0, stream>>>(dst, E, counts);
    scan_blk<<<nScanBlk, 256, 0, stream>>>(counts, excl, bsum, NN);
    scan_top<<<1, 256, 0, stream>>>(bsum, nScanBlk);
    scan_fin<<<nScanBlk, 256, 0, stream>>>(excl, bsum, row_ptr, fill, NN, E);
    scatter_kernel<<<eg, 256, 0, stream>>>(src, dst, E, fill, col_src);

    // ---- weight conversions (bf16, transposed k-blocked) ----
    wconv_kernel<<<(IN_F * 256 + 255) / 256, 256, 0, stream>>>(W0, IN_F, 256, w0h);
    wconv_kernel<<<(256 * 256 + 255) / 256, 256, 0, stream>>>(W1, 256, 256, w1h);
    wconv_kernel<<<(256 * 256 + 255) / 256, 256, 0, stream>>>(W2, 256, 256, w2h);
    wconv_kernel<<<(256 * 64 + 255) / 256, 256, 0, stream>>>(W3, 256, 64, w3h);

    const int gemmGrid = (NN + 63) / 64;  // 782
    const int waveBlocks = (NN + 3) / 4;  // 12500

    // ---- layer 0 (K=128, N=256, H=4): A = h fp32, converted in-register ----
    gemm_mfma_eler<256, 4, true><<<gemmGrid, 256, 0, stream>>>(h, w0h, zt, al0, ar0, el, er, NN, IN_F);
    agg_fused<4, true><<<waveBlocks, 256, 0, stream>>>(zt, el, er, row_ptr, col_src, nullptr, Abf);

    // ---- layer 1 ----
    gemm_mfma_eler<256, 4, false><<<gemmGrid, 256, 0, stream>>>(Abf, w1h, zt, al1, ar1, el, er, NN, 256);
    agg_fused<4, true><<<waveBlocks, 256, 0, stream>>>(zt, el, er, row_ptr, col_src, nullptr, Abf);

    // ---- layer 2 ----
    gemm_mfma_eler<256, 4, false><<<gemmGrid, 256, 0, stream>>>(Abf, w2h, zt, al2, ar2, el, er, NN, 256);
    agg_fused<4, true><<<waveBlocks, 256, 0, stream>>>(zt, el, er, row_ptr, col_src, nullptr, Abf);

    // ---- layer 3 (K=256, N=64, H=1) ----
    gemm_mfma_eler<64, 1, false><<<gemmGrid, 256, 0, stream>>>(Abf, w3h, zt, al3, ar3, el, er, NN, 256);
    agg_fused<1, false><<<waveBlocks, 256, 0, stream>>>(zt, el, er, row_ptr, col_src, bufA, nullptr);

    // ---- pooling + head ----
    pool_kernel<<<GG, 256, 0, stream>>>(bufA, gid, pooled, gcnt);
    head_kernel<<<1, 64, 0, stream>>>(pooled, gcnt, fc1w, fc1b, fc2w, fc2b, (float*)d_out);
}

// Round 13
// 531.685 us; speedup vs baseline: 1.4735x; 1.1370x over previous
//
#include <hip/hip_runtime.h>
#include <hip/hip_bf16.h>
#include <math.h>

#define NN 50000
#define IN_F 128
#define DD 64
#define HH 4
#define CC 10
#define GG 64
#define NEG_SLOPE 0.2f

typedef __attribute__((ext_vector_type(8))) short bf16x8;
typedef __attribute__((ext_vector_type(4))) float f32x4;
typedef __attribute__((ext_vector_type(4))) unsigned short u16x4;

__device__ inline ushort f2bf(float f) {
    unsigned u = __float_as_uint(f);
    unsigned r = (u + 0x7fffu + ((u >> 16) & 1u)) >> 16;
    return (ushort)r;
}
__device__ inline float bf2f(ushort b) { return __uint_as_float(((unsigned)b) << 16); }

// fp8 e4m3fn software encode (RNE) — validated in R9 (absmax 0.0)
__device__ inline unsigned f2fp8(float f) {
    float a = fabsf(f);
    a = fminf(a, 448.f);
    unsigned s = (__float_as_uint(f) >> 31) << 7;
    unsigned bits;
    if (a < 0.015625f) {  // < 2^-6: denormal, value = m * 2^-9
        bits = (unsigned)__float2int_rn(a * 512.f);
    } else {
        unsigned u = __float_as_uint(a);
        u += 0x7ffffu + ((u >> 20) & 1u);  // RNE at dropped bit 20
        bits = (u >> 20) - (120u << 3);
        bits = min(bits, 0x7Eu);
    }
    return s | bits;
}

#if defined(__has_builtin)
#if __has_builtin(__builtin_amdgcn_cvt_f32_fp8)
#define HAVE_CVT_FP8 1
#endif
#endif

template <int SEL>
__device__ inline float fp8dec(unsigned w) {
#ifdef HAVE_CVT_FP8
    return __builtin_amdgcn_cvt_f32_fp8((int)w, SEL);
#else
    unsigned b = (w >> (8 * SEL)) & 0xffu;
    unsigned u = ((b & 0x80u) << 24) | ((b & 0x7fu) << 20);
    return __uint_as_float(u) * 0x1p120f;
#endif
}

// ---------------- wave helpers ----------------
__device__ inline float wave_max(float v) {
#pragma unroll
    for (int o = 32; o > 0; o >>= 1) v = fmaxf(v, __shfl_xor(v, o));
    return v;
}
__device__ inline float wave_sum(float v) {
#pragma unroll
    for (int o = 32; o > 0; o >>= 1) v += __shfl_xor(v, o);
    return v;
}

// ---------------- CSR build ----------------
__global__ void hist_kernel(const int* __restrict__ dst, int E, int* __restrict__ counts) {
    int i = blockIdx.x * blockDim.x + threadIdx.x;
    if (i < E) atomicAdd(&counts[dst[i]], 1);
}

__global__ __launch_bounds__(256) void scan_blk(const int* __restrict__ counts,
                                                int* __restrict__ excl,
                                                int* __restrict__ bsum, int n) {
    __shared__ int sh[256];
    int t = threadIdx.x;
    int i = blockIdx.x * 256 + t;
    int v = (i < n) ? counts[i] : 0;
    sh[t] = v;
    __syncthreads();
#pragma unroll
    for (int o = 1; o < 256; o <<= 1) {
        int u = (t >= o) ? sh[t - o] : 0;
        __syncthreads();
        sh[t] += u;
        __syncthreads();
    }
    if (i < n) excl[i] = sh[t] - v;
    if (t == 255) bsum[blockIdx.x] = sh[255];
}

__global__ __launch_bounds__(256) void scan_top(int* __restrict__ bsum, int nb) {
    __shared__ int sh[256];
    int t = threadIdx.x;
    int v = (t < nb) ? bsum[t] : 0;
    sh[t] = v;
    __syncthreads();
#pragma unroll
    for (int o = 1; o < 256; o <<= 1) {
        int u = (t >= o) ? sh[t - o] : 0;
        __syncthreads();
        sh[t] += u;
        __syncthreads();
    }
    if (t < nb) bsum[t] = sh[t] - v;  // exclusive
}

__global__ __launch_bounds__(256) void scan_fin(const int* __restrict__ excl,
                                                const int* __restrict__ bsum,
                                                int* __restrict__ row_ptr,
                                                int* __restrict__ fill, int n, int E) {
    int i = blockIdx.x * blockDim.x + threadIdx.x;
    if (i < n) {
        int r = excl[i] + bsum[i >> 8];
        row_ptr[i] = r;
        fill[i] = r;
    }
    if (i == 0) row_ptr[n] = E;
}

__global__ void scatter_kernel(const int* __restrict__ src, const int* __restrict__ dst,
                               int E, int* __restrict__ fill, int* __restrict__ col_src) {
    int i = blockIdx.x * blockDim.x + threadIdx.x;
    if (i < E) {
        int p = atomicAdd(&fill[dst[i]], 1);
        col_src[p] = src[i];
    }
}

// ---------------- all W -> transposed, k-blocked, bf16 (single launch) ----------------
__global__ void wconv_all(const float* __restrict__ W0, const float* __restrict__ W1,
                          const float* __restrict__ W2, const float* __restrict__ W3,
                          ushort* __restrict__ o0, ushort* __restrict__ o1,
                          ushort* __restrict__ o2, ushort* __restrict__ o3) {
    int i = blockIdx.x * blockDim.x + threadIdx.x;
    const float* W;
    ushort* out;
    int N, rel;
    if (i < 32768) { W = W0; out = o0; N = 256; rel = i; }
    else if (i < 98304) { W = W1; out = o1; N = 256; rel = i - 32768; }
    else if (i < 163840) { W = W2; out = o2; N = 256; rel = i - 98304; }
    else if (i < 180224) { W = W3; out = o3; N = 64; rel = i - 163840; }
    else return;
    int k = rel / N, n = rel - k * N;
    size_t o = ((size_t)(k >> 5) * N + n) * 32 + (k & 31);
    out[o] = f2bf(W[rel]);
}

// ---------------- MFMA GEMM (bf16) + fused el/er, full double-buffer (A regs + W LDS) ----------------
// A: AF32 ? fp32 [M][K] (convert in-register) : bf16 [M][K].
// W: blocked [K/32][N][32] bf16. z out: H=4 -> fp8 packed [r][d][h]; H=1 -> bf16 [r][d].
template <int N, int H, bool AF32>
__global__ __launch_bounds__(256) void gemm_mfma_eler(
    const void* __restrict__ A0,
    const ushort* __restrict__ Wthi,
    void* __restrict__ ztv, const float* __restrict__ al, const float* __restrict__ ar,
    float* __restrict__ el, float* __restrict__ er, int M, int K) {
    constexpr int NT = N / 16;
    __shared__ ushort Bh[2][N][34];  // 68B row stride (odd bank count) -> near-uniform spread
    const int t = threadIdx.x;
    const int w = t >> 6, lane = t & 63;
    const int cl = lane & 15, g = lane >> 4;
    const int bm = blockIdx.x * 64;
    const int arow = bm + 16 * w + cl;
    const bool aval = arow < M;
    const size_t abase = (size_t)arow * K;
    const float* Af = (const float*)A0;
    const ushort* Abf = (const ushort*)A0;

    f32x4 acc[NT];
#pragma unroll
    for (int nt = 0; nt < NT; ++nt) acc[nt] = (f32x4){0.f, 0.f, 0.f, 0.f};

    const int nkb = K >> 5;

    // raw A-prefetch registers (kb=0)
    float4 fa0 = {0, 0, 0, 0}, fa1 = {0, 0, 0, 0};
    bf16x8 araw = {0, 0, 0, 0, 0, 0, 0, 0};
    if (aval) {
        if (AF32) {
            fa0 = *(const float4*)(Af + abase + g * 8);
            fa1 = *(const float4*)(Af + abase + g * 8 + 4);
        } else {
            araw = *(const bf16x8*)(Abf + abase + g * 8);
        }
    }
    // prologue: stage W kb=0 into buffer 0
    if (t < N) {
        const float4* gs = (const float4*)(Wthi + (size_t)t * 32);
#pragma unroll
        for (int q = 0; q < 4; ++q) *(float4*)&Bh[0][t][q * 8] = gs[q];
    }
    __syncthreads();

    for (int kb = 0; kb < nkb; ++kb) {
        const int cur = kb & 1;
        // materialize current A fragment (VALU only)
        bf16x8 a_cur;
        if (AF32) {
            float fv[8] = {fa0.x, fa0.y, fa0.z, fa0.w, fa1.x, fa1.y, fa1.z, fa1.w};
#pragma unroll
            for (int q = 0; q < 8; ++q) a_cur[q] = (short)f2bf(fv[q]);
        } else {
            a_cur = araw;
        }
        // prefetch next K-step operands (consumed after the MFMA block)
        float4 rn0, rn1, rn2, rn3;
        const bool pf = (kb + 1 < nkb);
        if (pf && t < N) {
            const float4* gs = (const float4*)(Wthi + ((size_t)(kb + 1) * N + t) * 32);
            rn0 = gs[0]; rn1 = gs[1]; rn2 = gs[2]; rn3 = gs[3];
        }
        if (pf && aval) {
            if (AF32) {
                fa0 = *(const float4*)(Af + abase + (kb + 1) * 32 + g * 8);
                fa1 = *(const float4*)(Af + abase + (kb + 1) * 32 + g * 8 + 4);
            } else {
                araw = *(const bf16x8*)(Abf + abase + (kb + 1) * 32 + g * 8);
            }
        }
#pragma unroll
        for (int nt = 0; nt < NT; ++nt) {
            bf16x8 b_hi = *(const bf16x8*)&Bh[cur][16 * nt + cl][g * 8];
            acc[nt] = __builtin_amdgcn_mfma_f32_16x16x32_bf16(a_cur, b_hi, acc[nt], 0, 0, 0);
        }
        // write prefetched W tile to the other buffer
        if (pf && t < N) {
            *(float4*)&Bh[cur ^ 1][t][0]  = rn0;
            *(float4*)&Bh[cur ^ 1][t][8]  = rn1;
            *(float4*)&Bh[cur ^ 1][t][16] = rn2;
            *(float4*)&Bh[cur ^ 1][t][24] = rn3;
        }
        __syncthreads();
    }

    // z store. Lane holds C[r0+j][16nt+cl], r0 = bm+16w+4g.
    const int r0 = bm + 16 * w + 4 * g;
    if (H == 4) {
        unsigned char* zf8 = (unsigned char*)ztv;
#pragma unroll
        for (int tt = 0; tt < 4; ++tt) {
#pragma unroll
            for (int j = 0; j < 4; ++j) {
                int r = r0 + j;
                if (r < M) {
                    unsigned pw = f2fp8(acc[tt][j]) | (f2fp8(acc[4 + tt][j]) << 8) |
                                  (f2fp8(acc[8 + tt][j]) << 16) | (f2fp8(acc[12 + tt][j]) << 24);
                    *(unsigned*)&zf8[(size_t)r * 256 + (16 * tt + cl) * 4] = pw;
                }
            }
        }
    } else {
        ushort* zt = (ushort*)ztv;
#pragma unroll
        for (int nt = 0; nt < NT; ++nt) {
#pragma unroll
            for (int j = 0; j < 4; ++j) {
                int r = r0 + j;
                if (r < M) zt[(size_t)r * N + 16 * nt + cl] = f2bf(acc[nt][j]);
            }
        }
    }
    // fused el/er
#pragma unroll
    for (int h = 0; h < H; ++h) {
        float pl[4] = {0.f, 0.f, 0.f, 0.f};
        float pr[4] = {0.f, 0.f, 0.f, 0.f};
#pragma unroll
        for (int tt = 0; tt < 4; ++tt) {
            int nt = 4 * h + tt;
            float av = al[h * DD + 16 * tt + cl];
            float rv = ar[h * DD + 16 * tt + cl];
#pragma unroll
            for (int j = 0; j < 4; ++j) {
                pl[j] += acc[nt][j] * av;
                pr[j] += acc[nt][j] * rv;
            }
        }
#pragma unroll
        for (int j = 0; j < 4; ++j) {
#pragma unroll
            for (int o = 1; o < 16; o <<= 1) {
                pl[j] += __shfl_xor(pl[j], o);
                pr[j] += __shfl_xor(pr[j], o);
            }
        }
        if (cl == 0) {
#pragma unroll
            for (int j = 0; j < 4; ++j) {
                int r = r0 + j;
                if (r < M) {
                    el[(size_t)r * H + h] = pl[j];
                    er[(size_t)r * H + h] = pr[j];
                }
            }
        }
    }
}

// ---------------- fused attention + aggregation: one wave per dst ----------------
// phase A (lane=edge): alpha computed once per edge -> per-wave LDS
// phase B (lane=feature): acc[h] += alpha[j][h] * z[src_j]  (z: fp8 H=4, bf16 H=1)
// OUTBF: write bf16 (feeds next GEMM); else fp32 (layer 3, feeds pool)
template <int H, bool OUTBF>
__global__ __launch_bounds__(256) void agg_fused(const void* __restrict__ ztv,
                                                 const float* __restrict__ el,
                                                 const float* __restrict__ er,
                                                 const int* __restrict__ row_ptr,
                                                 const int* __restrict__ col_src,
                                                 float* __restrict__ outf,
                                                 ushort* __restrict__ obf) {
    __shared__ float alf[4][64][H];  // per-wave alpha slab
    __shared__ int als[4][64];       // per-wave src ids
    const unsigned char* zf8 = (const unsigned char*)ztv;
    const ushort* zt16 = (const ushort*)ztv;
    const int wid = threadIdx.x >> 6;
    const int lane = threadIdx.x & 63;
    int v = blockIdx.x * 4 + wid;
    if (v >= NN) return;
    int start = row_ptr[v], end = row_ptr[v + 1];
    int deg = end - start;
    float erd[H], acc[H];
#pragma unroll
    for (int h = 0; h < H; ++h) {
        erd[h] = er[(size_t)v * H + h];
        acc[h] = 0.f;
    }

    auto agg_chunk = [&](int cnt) {
        int j = 0;
        for (; j + 4 <= cnt; j += 4) {
            int s0 = als[wid][j + 0], s1 = als[wid][j + 1];
            int s2 = als[wid][j + 2], s3 = als[wid][j + 3];
            if (H == 4) {
                f32x4 a0 = *(const f32x4*)&alf[wid][j + 0][0];
                f32x4 a1 = *(const f32x4*)&alf[wid][j + 1][0];
                f32x4 a2 = *(const f32x4*)&alf[wid][j + 2][0];
                f32x4 a3 = *(const f32x4*)&alf[wid][j + 3][0];
                unsigned z0 = *(const unsigned*)&zf8[(size_t)s0 * 256 + lane * 4];
                unsigned z1 = *(const unsigned*)&zf8[(size_t)s1 * 256 + lane * 4];
                unsigned z2 = *(const unsigned*)&zf8[(size_t)s2 * 256 + lane * 4];
                unsigned z3 = *(const unsigned*)&zf8[(size_t)s3 * 256 + lane * 4];
                acc[0] += a0[0] * fp8dec<0>(z0) + a1[0] * fp8dec<0>(z1) + a2[0] * fp8dec<0>(z2) + a3[0] * fp8dec<0>(z3);
                acc[1] += a0[1] * fp8dec<1>(z0) + a1[1] * fp8dec<1>(z1) + a2[1] * fp8dec<1>(z2) + a3[1] * fp8dec<1>(z3);
                acc[2] += a0[2] * fp8dec<2>(z0) + a1[2] * fp8dec<2>(z1) + a2[2] * fp8dec<2>(z2) + a3[2] * fp8dec<2>(z3);
                acc[3] += a0[3] * fp8dec<3>(z0) + a1[3] * fp8dec<3>(z1) + a2[3] * fp8dec<3>(z2) + a3[3] * fp8dec<3>(z3);
            } else {
                float a0 = alf[wid][j + 0][0], a1 = alf[wid][j + 1][0];
                float a2 = alf[wid][j + 2][0], a3 = alf[wid][j + 3][0];
                ushort z0 = zt16[(size_t)s0 * 64 + lane];
                ushort z1 = zt16[(size_t)s1 * 64 + lane];
                ushort z2 = zt16[(size_t)s2 * 64 + lane];
                ushort z3 = zt16[(size_t)s3 * 64 + lane];
                acc[0] += a0 * bf2f(z0);
                acc[0] += a1 * bf2f(z1);
                acc[0] += a2 * bf2f(z2);
                acc[0] += a3 * bf2f(z3);
            }
        }
        for (; j < cnt; ++j) {
            int s = als[wid][j];
            if (H == 4) {
                f32x4 a = *(const f32x4*)&alf[wid][j][0];
                unsigned z = *(const unsigned*)&zf8[(size_t)s * 256 + lane * 4];
                acc[0] += a[0] * fp8dec<0>(z);
                acc[1] += a[1] * fp8dec<1>(z);
                acc[2] += a[2] * fp8dec<2>(z);
                acc[3] += a[3] * fp8dec<3>(z);
            } else {
                acc[0] += alf[wid][j][0] * bf2f(zt16[(size_t)s * 64 + lane]);
            }
        }
    };

    if (deg <= 64) {
        bool valid = lane < deg;
        int s = col_src[valid ? start + lane : start];
        als[wid][lane] = s;
        float e[H];
        if (H == 4) {
            f32x4 ev = *(const f32x4*)&el[(size_t)s * 4];
#pragma unroll
            for (int h = 0; h < 4; ++h) {
                float x = ev[h] + erd[h];
                x = (x >= 0.f) ? x : NEG_SLOPE * x;
                e[h] = valid ? x : -1e30f;
            }
        } else {
            float x = el[s] + erd[0];
            x = (x >= 0.f) ? x : NEG_SLOPE * x;
            e[0] = valid ? x : -1e30f;
        }
#pragma unroll
        for (int h = 0; h < H; ++h) {
            float m = wave_max(e[h]);
            float ex = valid ? __expf(e[h] - m) : 0.f;
            float den = wave_sum(ex);
            alf[wid][lane][h] = ex * (1.f / den);
        }
        __builtin_amdgcn_wave_barrier();
        agg_chunk(deg);
    } else {
        float m[H];
#pragma unroll
        for (int h = 0; h < H; ++h) m[h] = -1e30f;
        for (int base = start; base < end; base += 64) {
            int i = base + lane;
            bool valid = i < end;
            int s = col_src[valid ? i : start];
#pragma unroll
            for (int h = 0; h < H; ++h) {
                float x = el[(size_t)s * H + h] + erd[h];
                x = (x >= 0.f) ? x : NEG_SLOPE * x;
                m[h] = fmaxf(m[h], valid ? x : -1e30f);
            }
        }
        float den[H];
#pragma unroll
        for (int h = 0; h < H; ++h) {
            m[h] = wave_max(m[h]);
            den[h] = 0.f;
        }
        for (int base = start; base < end; base += 64) {
            int i = base + lane;
            bool valid = i < end;
            int s = col_src[valid ? i : start];
#pragma unroll
            for (int h = 0; h < H; ++h) {
                float x = el[(size_t)s * H + h] + erd[h];
                x = (x >= 0.f) ? x : NEG_SLOPE * x;
                den[h] += valid ? __expf(x - m[h]) : 0.f;
            }
        }
        float inv[H];
#pragma unroll
        for (int h = 0; h < H; ++h) inv[h] = 1.f / wave_sum(den[h]);
        for (int base = start; base < end; base += 64) {
            int i = base + lane;
            bool valid = i < end;
            int s = col_src[valid ? i : start];
            als[wid][lane] = s;
#pragma unroll
            for (int h = 0; h < H; ++h) {
                float x = el[(size_t)s * H + h] + erd[h];
                x = (x >= 0.f) ? x : NEG_SLOPE * x;
                alf[wid][lane][h] = valid ? __expf(x - m[h]) * inv[h] : 0.f;
            }
            __builtin_amdgcn_wave_barrier();
            int cnt = min(64, end - base);
            agg_chunk(cnt);
            __builtin_amdgcn_wave_barrier();
        }
    }

#pragma unroll
    for (int h = 0; h < H; ++h) {
        float r = acc[h];
        r = (r > 0.f) ? r : 0.f;  // fused ReLU
        size_t idx = (size_t)v * H * DD + h * DD + lane;
        if (OUTBF) {
            obf[idx] = f2bf(r);
        } else {
            outf[idx] = r;
        }
    }
}

// ---------------- pooling (1024 threads: 16 waves per graph) ----------------
__device__ inline int lower_bound_dev(const int* a, int n, int v) {
    int lo = 0, hi = n;
    while (lo < hi) {
        int mid = (lo + hi) >> 1;
        if (a[mid] < v) lo = mid + 1; else hi = mid;
    }
    return lo;
}

__global__ __launch_bounds__(1024) void pool_kernel(const float* __restrict__ x,
                                                    const int* __restrict__ gid,
                                                    float* __restrict__ pooled,
                                                    float* __restrict__ gcnt) {
    int g = blockIdx.x;
    int start = lower_bound_dev(gid, NN, g);
    int end = lower_bound_dev(gid, NN, g + 1);
    int lane = threadIdx.x & 63;
    int w = threadIdx.x >> 6;
    float acc = 0.f;
    for (int i = start + w; i < end; i += 16) acc += x[(size_t)i * DD + lane];
    __shared__ float red[16][DD];
    red[w][lane] = acc;
    __syncthreads();
    if (w == 0) {
        float s = 0.f;
#pragma unroll
        for (int q = 0; q < 16; ++q) s += red[q][lane];
        pooled[g * DD + lane] = s;
        if (lane == 0) gcnt[g] = (float)(end - start);
    }
}

// ---------------- head ----------------
__global__ __launch_bounds__(64) void head_kernel(const float* __restrict__ pooled,
                                                  const float* __restrict__ gcnt,
                                                  const float* __restrict__ fc1w,
                                                  const float* __restrict__ fc1b,
                                                  const float* __restrict__ fc2w,
                                                  const float* __restrict__ fc2b,
                                                  float* __restrict__ out) {
    __shared__ float P[GG][DD + 1];
    __shared__ float Y1[GG][DD + 1];
    int g = threadIdx.x;
    float c = fmaxf(gcnt[g], 1.0f);
    for (int k = 0; k < DD; ++k) P[g][k] = pooled[g * DD + k] / c;
    __syncthreads();
    for (int j = 0; j < DD; ++j) {
        float s = fc1b[j];
        for (int k = 0; k < DD; ++k) s += P[g][k] * fc1w[k * DD + j];
        Y1[g][j] = (s > 0.f) ? s : expm1f(s);
    }
    __syncthreads();
    float y2[CC];
    for (int c2 = 0; c2 < CC; ++c2) {
        float s = fc2b[c2];
        for (int j = 0; j < DD; ++j) s += Y1[g][j] * fc2w[j * CC + c2];
        y2[c2] = s;
    }
    for (int c2 = 0; c2 < CC; ++c2) {
        float m = y2[c2];
#pragma unroll
        for (int o = 32; o > 0; o >>= 1) m = fmaxf(m, __shfl_xor(m, o));
        float sexp = __expf(y2[c2] - m);
#pragma unroll
        for (int o = 32; o > 0; o >>= 1) sexp += __shfl_xor(sexp, o);
        out[g * CC + c2] = y2[c2] - m - logf(sexp);
    }
}

// ---------------- launcher ----------------
extern "C" void kernel_launch(void* const* d_in, const int* in_sizes, int n_in,
                              void* d_out, int out_size, void* d_ws, size_t ws_size,
                              hipStream_t stream) {
    const float* h    = (const float*)d_in[0];
    const int* src    = (const int*)d_in[1];
    const int* dst    = (const int*)d_in[2];
    const int* gid    = (const int*)d_in[3];
    const float* W0   = (const float*)d_in[4];
    const float* al0  = (const float*)d_in[5];
    const float* ar0  = (const float*)d_in[6];
    const float* W1   = (const float*)d_in[7];
    const float* al1  = (const float*)d_in[8];
    const float* ar1  = (const float*)d_in[9];
    const float* W2   = (const float*)d_in[10];
    const float* al2  = (const float*)d_in[11];
    const float* ar2  = (const float*)d_in[12];
    const float* W3   = (const float*)d_in[13];
    const float* al3  = (const float*)d_in[14];
    const float* ar3  = (const float*)d_in[15];
    const float* fc1w = (const float*)d_in[16];
    const float* fc1b = (const float*)d_in[17];
    const float* fc2w = (const float*)d_in[18];
    const float* fc2b = (const float*)d_in[19];
    const int E = in_sizes[1];

    char* wsb = (char*)d_ws;
    size_t off = 0;
    auto alloc = [&](size_t bytes) -> void* {
        void* p = wsb + off;
        off = (off + bytes + 255) & ~(size_t)255;
        return p;
    };
    unsigned char* zf8 = (unsigned char*)alloc((size_t)NN * 256);  // z fp8 packed [v][d][h] (layers 0-2)
    ushort* zt16    = (ushort*)alloc((size_t)NN * DD * 2);         // z bf16 [v][d] (layer 3)
    ushort* Abf     = (ushort*)alloc((size_t)NN * 256 * 2);        // GEMM A input (bf16), layers 1-3
    float*  bufA    = (float*)alloc((size_t)NN * DD * 4);          // layer-3 output (fp32, for pool)
    float*  el      = (float*)alloc((size_t)NN * HH * 4);
    float*  er      = (float*)alloc((size_t)NN * HH * 4);
    int*    counts  = (int*)alloc((size_t)NN * 4);
    int*    row_ptr = (int*)alloc((size_t)(NN + 1) * 4);
    int*    fill    = (int*)alloc((size_t)NN * 4);
    int*    excl    = (int*)alloc((size_t)NN * 4);
    int*    bsum    = (int*)alloc((size_t)256 * 4);
    int*    col_src = (int*)alloc((size_t)E * 4);
    float*  pooled  = (float*)alloc((size_t)GG * DD * 4);
    float*  gcnt    = (float*)alloc((size_t)GG * 4);
    ushort* w0h     = (ushort*)alloc((size_t)IN_F * 256 * 2);
    ushort* w1h     = (ushort*)alloc((size_t)256 * 256 * 2);
    ushort* w2h     = (ushort*)alloc((size_t)256 * 256 * 2);
    ushort* w3h     = (ushort*)alloc((size_t)256 * 64 * 2);

    // ---- CSR build ----
    hipMemsetAsync(counts, 0, (size_t)NN * 4, stream);
    int eg = (E + 255) / 256;
    const int nScanBlk = (NN + 255) / 256;  // 196
    hist_kernel<<<eg, 256, 0, stream>>>(dst, E, counts);
    scan_blk<<<nScanBlk, 256, 0, stream>>>(counts, excl, bsum, NN);
    scan_top<<<1, 256, 0, stream>>>(bsum, nScanBlk);
    scan_fin<<<nScanBlk, 256, 0, stream>>>(excl, bsum, row_ptr, fill, NN, E);
    scatter_kernel<<<eg, 256, 0, stream>>>(src, dst, E, fill, col_src);

    // ---- weight conversions (single launch) ----
    wconv_all<<<(180224 + 255) / 256, 256, 0, stream>>>(W0, W1, W2, W3, w0h, w1h, w2h, w3h);

    const int gemmGrid = (NN + 63) / 64;  // 782
    const int waveBlocks = (NN + 3) / 4;  // 12500

    // ---- layer 0 (K=128, N=256, H=4): A = h fp32, converted in-register ----
    gemm_mfma_eler<256, 4, true><<<gemmGrid, 256, 0, stream>>>(h, w0h, zf8, al0, ar0, el, er, NN, IN_F);
    agg_fused<4, true><<<waveBlocks, 256, 0, stream>>>(zf8, el, er, row_ptr, col_src, nullptr, Abf);

    // ---- layer 1 ----
    gemm_mfma_eler<256, 4, false><<<gemmGrid, 256, 0, stream>>>(Abf, w1h, zf8, al1, ar1, el, er, NN, 256);
    agg_fused<4, true><<<waveBlocks, 256, 0, stream>>>(zf8, el, er, row_ptr, col_src, nullptr, Abf);

    // ---- layer 2 ----
    gemm_mfma_eler<256, 4, false><<<gemmGrid, 256, 0, stream>>>(Abf, w2h, zf8, al2, ar2, el, er, NN, 256);
    agg_fused<4, true><<<waveBlocks, 256, 0, stream>>>(zf8, el, er, row_ptr, col_src, nullptr, Abf);

    // ---- layer 3 (K=256, N=64, H=1): z bf16 ----
    gemm_mfma_eler<64, 1, false><<<gemmGrid, 256, 0, stream>>>(Abf, w3h, zt16, al3, ar3, el, er, NN, 256);
    agg_fused<1, false><<<waveBlocks, 256, 0, stream>>>(zt16, el, er, row_ptr, col_src, bufA, nullptr);

    // ---- pooling + head ----
    pool_kernel<<<GG, 1024, 0, stream>>>(bufA, gid, pooled, gcnt);
    head_kernel<<<1, 64, 0, stream>>>(pooled, gcnt, fc1w, fc1b, fc2w, fc2b, (float*)d_out);
}